// Round 3
// baseline (334.545 us; speedup 1.0000x reference)
//
#include <hip/hip_runtime.h>
#include <hip/hip_cooperative_groups.h>
#include <hip/hip_bf16.h>
#include <math.h>

namespace cg = cooperative_groups;

// Problem constants (fixed by setup_inputs)
#define B_     2
#define N_     2048
#define DA     128
#define H_     4
#define DH     32
#define DFF    512
#define DM     512
#define NT     512
#define NP     16384
#define MAXL   32    // max atoms per token group (validated in prior session)
#define LDSP   136   // padded LDS row stride (shorts): 2-way bank aliasing only

typedef short bf16x8 __attribute__((ext_vector_type(8)));   // 8 bf16 in 4 VGPRs
typedef float f32x4  __attribute__((ext_vector_type(4)));   // MFMA accumulator

__device__ __forceinline__ short bf16r(float x) {           // RNE fp32->bf16
    union { float f; unsigned u; } v; v.f = x;
    unsigned r = v.u + 0x7FFFu + ((v.u >> 16) & 1u);
    return (short)(r >> 16);
}
__device__ __forceinline__ float bf2f(short h) {
    union { unsigned u; float f; } v;
    v.u = ((unsigned)(unsigned short)h) << 16;
    return v.f;
}

// -------- MFMA GEMM cores ----------------------------------------------------
template<int K, int NTT>
__device__ __forceinline__ void gemm_lds(const short* __restrict__ Alds,
                                         const short* __restrict__ Bp,
                                         int nt0, int lane, f32x4* acc) {
    constexpr int KT = K / 32;
    const short* arow = Alds + (lane & 15) * LDSP + (lane >> 4) * 8;
    const short* bbase = Bp + nt0 * KT * 512 + lane * 8;
#pragma unroll
    for (int kt = 0; kt < KT; kt++) {
        bf16x8 a = *(const bf16x8*)(arow + kt * 32);
#pragma unroll
        for (int nt = 0; nt < NTT; nt++) {
            bf16x8 b = *(const bf16x8*)(bbase + (nt * KT + kt) * 512);
            acc[nt] = __builtin_amdgcn_mfma_f32_16x16x32_bf16(a, b, acc[nt], 0, 0, 0);
        }
    }
}

template<int K, int NTT>
__device__ __forceinline__ void gemm_glb(const short* __restrict__ A,
                                         const short* __restrict__ Bp,
                                         int m0, int nt0, int lane, f32x4* acc) {
    constexpr int KT = K / 32;
    const short* arow = A + (m0 + (lane & 15)) * K + (lane >> 4) * 8;
    const short* bbase = Bp + nt0 * KT * 512 + lane * 8;
#pragma unroll
    for (int kt = 0; kt < KT; kt++) {
        bf16x8 a = *(const bf16x8*)(arow + kt * 32);
#pragma unroll
        for (int nt = 0; nt < NTT; nt++) {
            bf16x8 b = *(const bf16x8*)(bbase + (nt * KT + kt) * 512);
            acc[nt] = __builtin_amdgcn_mfma_f32_16x16x32_bf16(a, b, acc[nt], 0, 0, 0);
        }
    }
}

// =============================================================================
// Single cooperative mega-kernel: 256 blocks x 512 threads (1 block/CU).
// Phases separated by grid.sync(); replaces 6 serialized kernel launches.
// =============================================================================
__global__ __launch_bounds__(512, 2) void mega(
        const float* __restrict__ c_atom, const float* __restrict__ plm,
        const int* __restrict__ pidx, const int* __restrict__ tok,
        const float* __restrict__ lnag, const float* __restrict__ lnab,
        const float* __restrict__ wq, const float* __restrict__ wk,
        const float* __restrict__ wv, const float* __restrict__ wg,
        const float* __restrict__ wo,
        const float* __restrict__ pbw, const float* __restrict__ pbb,
        const float* __restrict__ lnfg, const float* __restrict__ lnfb,
        const float* __restrict__ w1, const float* __restrict__ w2,
        const float* __restrict__ w3, const float* __restrict__ tw,
        const float* __restrict__ tb,
        float* __restrict__ out,
        int* __restrict__ cnt, int* __restrict__ tst, int* __restrict__ win,
        short* __restrict__ pqkvg, short* __restrict__ pwo,
        short* __restrict__ pw12, short* __restrict__ pw3,
        short* __restrict__ ptok,
        short* __restrict__ hln, short* __restrict__ atth,
        float* __restrict__ qbuf, float* __restrict__ qkvg,
        short* __restrict__ uh) {
    __shared__ __align__(16) char smraw[128 * LDSP * 2];   // 34816 B, phase-reused
    cg::grid_group grid = cg::this_grid();
    int blk = blockIdx.x;
    int tid = threadIdx.x;
    int lane = tid & 63, wave = tid >> 6;

    // ================= P0: weight pack + LN1 + hist/scan + pair winners ======
    if (blk < 84) {
        // weight pack: wave w of block b handles group g = b*8+w  (672 groups)
        int g = blk * 8 + wave;
        int quad = lane >> 4, nn = lane & 15;
        const float* src; short* dst; int stride;
        if (g < 128) {                   // Wqkvg: K=128, N=512, KT=4
            int kt = g & 3, nt = g >> 2;
            int n = nt * 16 + nn;
            const float* w = (n < 128) ? wq : (n < 256) ? wk : (n < 384) ? wv : wg;
            src = w + (kt * 32 + quad * 8) * 128 + (n & 127);
            dst = pqkvg + (g * 64 + lane) * 8;
            stride = 128;
        } else if (g < 160) {            // Wo: K=128, N=128
            int gg = g - 128; int kt = gg & 3, nt = gg >> 2;
            src = wo + (kt * 32 + quad * 8) * 128 + nt * 16 + nn;
            dst = pwo + (gg * 64 + lane) * 8;
            stride = 128;
        } else if (g < 416) {            // W12 interleaved: K=128, Npacked=1024
            int gg = g - 160; int kt = gg & 3, nt = gg >> 2;
            int n = nt * 16 + nn;        // even=w1, odd=w2, real col n>>1
            src = ((n & 1) ? w2 : w1) + (kt * 32 + quad * 8) * 512 + (n >> 1);
            dst = pw12 + (gg * 64 + lane) * 8;
            stride = 512;
        } else if (g < 544) {            // W3: K=512, N=128, KT=16
            int gg = g - 416; int kt = gg & 15, nt = gg >> 4;
            src = w3 + (kt * 32 + quad * 8) * 128 + nt * 16 + nn;
            dst = pw3 + (gg * 64 + lane) * 8;
            stride = 128;
        } else {                         // Wtok: K=128, N=512
            int gg = g - 544; int kt = gg & 3, nt = gg >> 2;
            src = tw + (kt * 32 + quad * 8) * 512 + nt * 16 + nn;
            dst = ptok + (gg * 64 + lane) * 8;
            stride = 512;
        }
#pragma unroll
        for (int j = 0; j < 8; j++) dst[j] = bf16r(src[j * stride]);
    } else if (blk < 116) {
        // LN1: 128 rows/block (4 thr/row, 32 cols each) -> bf16 hln
        int rowg = (blk - 84) * 128 + (tid >> 2);       // 0..4095
        int sub = tid & 3;
        const float* xr = c_atom + rowg * DA + sub * 32;
        float4 v[8];
        float s = 0.f, sq = 0.f;
#pragma unroll
        for (int i = 0; i < 8; i++) {
            v[i] = *(const float4*)(xr + i * 4);
            s  += v[i].x + v[i].y + v[i].z + v[i].w;
            sq += v[i].x * v[i].x + v[i].y * v[i].y + v[i].z * v[i].z + v[i].w * v[i].w;
        }
        s += __shfl_xor(s, 1); sq += __shfl_xor(sq, 1);
        s += __shfl_xor(s, 2); sq += __shfl_xor(sq, 2);
        float mean = s * (1.f / 128.f);
        float var = sq * (1.f / 128.f) - mean * mean;
        float inv = rsqrtf(var + 1e-5f);
        const float* gp = lnag + sub * 32;
        const float* bp = lnab + sub * 32;
        short* dst = hln + rowg * DA + sub * 32;
#pragma unroll
        for (int i = 0; i < 8; i++) {
            dst[i * 4 + 0] = bf16r((v[i].x - mean) * inv * gp[i * 4 + 0] + bp[i * 4 + 0]);
            dst[i * 4 + 1] = bf16r((v[i].y - mean) * inv * gp[i * 4 + 1] + bp[i * 4 + 1]);
            dst[i * 4 + 2] = bf16r((v[i].z - mean) * inv * gp[i * 4 + 2] + bp[i * 4 + 2]);
            dst[i * 4 + 3] = bf16r((v[i].w - mean) * inv * gp[i * 4 + 3] + bp[i * 4 + 3]);
        }
    } else if (blk == 116) {
        // histogram + segmented exclusive scan (1024 entries, 512 threads)
        int* c  = (int*)smraw;
        int* sb = c + 1024;
        c[tid] = 0; c[tid + 512] = 0;
        __syncthreads();
#pragma unroll
        for (int i = 0; i < 8; i++) {
            int idx = tid + i * 512;            // 0..4095
            int b = idx >> 11;
            atomicAdd(&c[b * NT + tok[idx]], 1);
        }
        __syncthreads();
        int v0 = c[tid], v1 = c[tid + 512];
        int* cur = c;
        int* alt = sb;
        for (int d = 1; d < 512; d <<= 1) {
            int y0 = cur[tid];       if (tid >= d) y0 += cur[tid - d];
            int y1 = cur[tid + 512]; if (tid >= d) y1 += cur[tid + 512 - d];
            alt[tid] = y0; alt[tid + 512] = y1;
            __syncthreads();
            int* t_ = cur; cur = alt; alt = t_;
        }
        tst[tid] = cur[tid] - v0;          cnt[tid] = v0;
        tst[tid + 512] = cur[tid + 512] - v1; cnt[tid + 512] = v1;
    } else if (blk < 133) {
        // pair winners: 2048 pairs/block; poison (0xAA.. < 0) = no winner
        int base = (blk - 117) * 2048;
#pragma unroll
        for (int i = 0; i < 4; i++) {
            int p = base + i * 512 + tid;       // 0..32767
            int b = p >> 14, pp = p & (NP - 1);
            int src = pidx[p * 2], dst = pidx[p * 2 + 1];
            if (tok[b * N_ + src] == tok[b * N_ + dst])
                atomicMax(&win[(b * N_ + src) * MAXL + (dst & 31)], pp + 1);
        }
    }
    grid.sync();

    // ================= P1: qkvg = hln @ [wq|wk|wv|wg]  (fp32 out) ============
    {
        int xb = blk & 63, yb = blk >> 6;          // 64-row block, 128-col block
        int m0 = xb * 64 + (wave & 3) * 16;
        int nt0 = yb * 8 + (wave >> 2) * 4;
        f32x4 acc[4];
#pragma unroll
        for (int i = 0; i < 4; i++)
#pragma unroll
            for (int r = 0; r < 4; r++) acc[i][r] = 0.f;
        gemm_glb<128, 4>(hln, pqkvg, m0, nt0, lane, acc);
        int r0 = m0 + ((lane >> 4) << 2);
        int cc = lane & 15;
#pragma unroll
        for (int nt = 0; nt < 4; nt++) {
            int col = (nt0 + nt) * 16 + cc;
#pragma unroll
            for (int r = 0; r < 4; r++) qkvg[(r0 + r) * 512 + col] = acc[nt][r];
        }
    }
    grid.sync();

    // ================= P2: grouped attention, online softmax, in-register ====
    {
        int team = tid >> 7;                      // 4 teams of 128 threads
        int t127 = tid & 127;
        int h = t127 >> 5, d = t127 & 31;
        const float scale = 0.17677669529663687f; // 1/sqrt(32)
        for (int i = 0; i < 4; i++) {
            int atom = blk * 16 + team * 4 + i;   // 0..4095 (contiguous/team)
            int b = atom >> 11;
            int t = tok[atom];
            int start = tst[b * NT + t];
            int L = cnt[b * NT + t];
            if (L > MAXL) L = MAXL;
            float qv = qkvg[atom * 512 + h * DH + d];
            const float* kbase = qkvg + (size_t)(b * N_ + start) * 512 + 128 + h * DH + d;
            const float* vbase = kbase + 128;
            const int* wbase = win + atom * MAXL;
            float mrun = -1e30f, denom = 0.f, acc = 0.f;
            for (int j0 = 0; j0 < L; j0 += 8) {
                int m8 = L - j0; if (m8 > 8) m8 = 8;
                float kv[8], vv[8]; int pw[8];
#pragma unroll
                for (int u = 0; u < 8; u++) {
                    if (u < m8) {
                        kv[u] = kbase[(j0 + u) * 512];
                        vv[u] = vbase[(j0 + u) * 512];
                        pw[u] = wbase[(start + j0 + u) & 31];
                    }
                }
                float s[8];
#pragma unroll
                for (int u = 0; u < 8; u++) {
                    if (u < m8) {
                        float sv = qv * kv[u];
#pragma unroll
                        for (int mm = 16; mm; mm >>= 1) sv += __shfl_xor(sv, mm, 32);
                        sv *= scale;
                        if (pw[u] > 0) {          // inline bias from winning pair
                            const float* pl = plm + (size_t)(b * NP + pw[u] - 1) * 16;
                            float bsum = pbb[h];
#pragma unroll
                            for (int f = 0; f < 16; f++) bsum += pl[f] * pbw[f * H_ + h];
                            sv += bsum;
                        }
                        s[u] = sv;
                    }
                }
                float cmax = -1e30f;
#pragma unroll
                for (int u = 0; u < 8; u++)
                    if (u < m8) cmax = fmaxf(cmax, s[u]);
                float mnew = fmaxf(mrun, cmax);
                float rs = expf(mrun - mnew);     // first iter: exp(-inf)=0
                denom *= rs; acc *= rs;
#pragma unroll
                for (int u = 0; u < 8; u++) {
                    if (u < m8) {
                        float p = expf(s[u] - mnew);
                        denom += p;
                        acc += p * vv[u];
                    }
                }
                mrun = mnew;
            }
            atth[atom * DA + h * DH + d] = bf16r(acc / denom);
        }
    }
    grid.sync();

    // ================= P3: outproj + gate/residual + LN2 + ffn1 ==============
    {
        short* alds = (short*)smraw;              // 128 x LDSP bf16
        int xb = blk & 31, yb = blk >> 5;         // 128-row block, col-eighth
        int m0 = xb * 128 + wave * 16;
        int quad = lane >> 4, cc = lane & 15;
        f32x4 acc[8];
#pragma unroll
        for (int i = 0; i < 8; i++)
#pragma unroll
            for (int r = 0; r < 4; r++) acc[i][r] = 0.f;
        gemm_glb<128, 8>(atth, pwo, m0, 0, lane, acc);
        float rsum[4], rsq[4];
#pragma unroll
        for (int r = 0; r < 4; r++) {
            int row = m0 + quad * 4 + r;
            float s = 0.f, sq = 0.f;
#pragma unroll
            for (int nt = 0; nt < 8; nt++) {
                int col = nt * 16 + cc;
                float g = qkvg[row * 512 + 384 + col];
                float sg = 1.f / (1.f + expf(-g));
                float val = c_atom[row * DA + col] + sg * acc[nt][r];
                acc[nt][r] = val;
                s += val; sq += val * val;
                if (yb == 0) qbuf[row * DA + col] = val;
            }
            rsum[r] = s; rsq[r] = sq;
        }
#pragma unroll
        for (int m = 1; m < 16; m <<= 1) {
#pragma unroll
            for (int r = 0; r < 4; r++) {
                rsum[r] += __shfl_xor(rsum[r], m);
                rsq[r]  += __shfl_xor(rsq[r], m);
            }
        }
#pragma unroll
        for (int r = 0; r < 4; r++) {
            float mean = rsum[r] * (1.f / 128.f);
            float var = rsq[r] * (1.f / 128.f) - mean * mean;
            float inv = rsqrtf(var + 1e-5f);
            int lrow = wave * 16 + quad * 4 + r;
#pragma unroll
            for (int nt = 0; nt < 8; nt++) {
                int col = nt * 16 + cc;
                alds[lrow * LDSP + col] = bf16r((acc[nt][r] - mean) * inv * lnfg[col] + lnfb[col]);
            }
        }
        __syncthreads();
        // ffn1: u = bf16( silu(h@w1) * (h@w2) ), packed tiles nt0..nt0+7
        int nt0 = yb * 8;
        f32x4 acc2[8];
#pragma unroll
        for (int i = 0; i < 8; i++)
#pragma unroll
            for (int r = 0; r < 4; r++) acc2[i][r] = 0.f;
        gemm_lds<128, 8>(alds + wave * 16 * LDSP, pw12, nt0, lane, acc2);
        int r0 = m0 + quad * 4;
#pragma unroll
        for (int nt = 0; nt < 8; nt++) {
            int col8 = (nt0 + nt) * 8 + (cc >> 1);    // real u column
#pragma unroll
            for (int r = 0; r < 4; r++) {
                float v = acc2[nt][r];
                float p = __shfl_xor(v, 1);           // partner (w2) value
                if (!(lane & 1)) {                    // even lane holds w1 result
                    float sil = v / (1.f + expf(-v));
                    uh[(r0 + r) * DFF + col8] = bf16r(sil * p);
                }
            }
        }
    }
    grid.sync();

    // ================= P4: q2 = bf16(qbuf + u @ w3)   (K=512) ================
    {
        short* q2h = atth;                        // atth dead; reuse as q2h
        int m0 = blk * 16;
        int nt0 = wave;                           // 8 col tiles of 16
        f32x4 acc[1];
#pragma unroll
        for (int r = 0; r < 4; r++) acc[0][r] = 0.f;
        gemm_glb<512, 1>(uh, pw3, m0, nt0, lane, acc);
        int r0 = m0 + ((lane >> 4) << 2);
        int cc = lane & 15;
        int col = nt0 * 16 + cc;
#pragma unroll
        for (int r = 0; r < 4; r++) {
            int row = r0 + r;
            q2h[row * DA + col] = bf16r(qbuf[row * DA + col] + acc[0][r]);
        }
    }
    grid.sync();

    // ================= P5: segment-mean + token projection ===================
    {
        const short* q2h = atth;
        short* alds = (short*)smraw;              // 64 x LDSP bf16
        int xb = blk & 15, yb = blk >> 4;         // 64-token block, 32-col block
        int tt = tid >> 3, sub = tid & 7;         // 8 thr/token, 16 cols each
        int token = xb * 64 + tt;                 // linear (b*NT + t)
        int start = tst[token], n = cnt[token];
        int b = token >> 9;
        float accm[16];
#pragma unroll
        for (int i = 0; i < 16; i++) accm[i] = 0.f;
        const short* rp = q2h + (size_t)(b * N_ + start) * DA + sub * 16;
        for (int a = 0; a < n; a++) {
            bf16x8 v0 = *(const bf16x8*)(rp + a * DA);
            bf16x8 v1 = *(const bf16x8*)(rp + a * DA + 8);
#pragma unroll
            for (int j = 0; j < 8; j++) {
                accm[j]     += bf2f(v0[j]);
                accm[8 + j] += bf2f(v1[j]);
            }
        }
        float inv = (n > 0) ? 1.f / (float)n : 0.f;
        short* dst = alds + tt * LDSP + sub * 16;
#pragma unroll
        for (int i = 0; i < 16; i++) dst[i] = bf16r(accm[i] * inv);
        __syncthreads();

        int nt0 = yb * 2 + (wave >> 2);           // 32 col tiles of 16 total
        f32x4 acc[1];
#pragma unroll
        for (int r = 0; r < 4; r++) acc[0][r] = 0.f;
        gemm_lds<128, 1>(alds + (wave & 3) * 16 * LDSP, ptok, nt0, lane, acc);
        int r0 = xb * 64 + (wave & 3) * 16 + ((lane >> 4) << 2);
        int cc = lane & 15;
        int col = nt0 * 16 + cc;
        float bv = tb[col];
#pragma unroll
        for (int r = 0; r < 4; r++)
            out[(size_t)(r0 + r) * DM + col] = acc[0][r] + bv;
    }
}

extern "C" void kernel_launch(void* const* d_in, const int* in_sizes, int n_in,
                              void* d_out, int out_size, void* d_ws, size_t ws_size,
                              hipStream_t stream) {
    const float* c_atom  = (const float*)d_in[0];
    const float* p_lm    = (const float*)d_in[1];
    const int*   p_idx   = (const int*)d_in[2];
    const int*   tok     = (const int*)d_in[3];
    // d_in[4] = n_tokens (512, hardcoded)
    const float* ln_a_g  = (const float*)d_in[5];
    const float* ln_a_b  = (const float*)d_in[6];
    const float* w_q     = (const float*)d_in[7];
    const float* w_k     = (const float*)d_in[8];
    const float* w_v     = (const float*)d_in[9];
    const float* w_g     = (const float*)d_in[10];
    const float* w_o     = (const float*)d_in[11];
    const float* pb_w    = (const float*)d_in[12];
    const float* pb_b    = (const float*)d_in[13];
    const float* ln_f_g  = (const float*)d_in[14];
    const float* ln_f_b  = (const float*)d_in[15];
    const float* sw_w1   = (const float*)d_in[16];
    const float* sw_w2   = (const float*)d_in[17];
    const float* sw_w3   = (const float*)d_in[18];
    const float* tok_w   = (const float*)d_in[19];
    const float* tok_b   = (const float*)d_in[20];
    float* out = (float*)d_out;

    // ---------------- workspace layout (no aliasing hazards) -----------------
    float* ws = (float*)d_ws;
    int*   cnt   = (int*)ws;                       // 1024 i
    int*   tst   = cnt + 1024;                     // 1024 i
    int*   win   = tst + 1024;                     // 131072 i (poison = no winner)
    short* pqkvg = (short*)(win + 131072);         // 65536 bf16
    short* pwo   = pqkvg + 65536;                  // 16384 bf16
    short* pw12  = pwo + 16384;                    // 131072 bf16
    short* pw3   = pw12 + 131072;                  // 65536 bf16
    short* ptok  = pw3 + 65536;                    // 65536 bf16
    short* atth  = ptok + 65536;                   // 524288 bf16 [reused as q2h]
    float* qbuf  = (float*)(atth + 524288);        // 524288 f
    float* qkvg  = qbuf + 524288;                  // 2097152 f
    short* uh    = (short*)(qkvg + 2097152);       // 2097152 bf16
    short* hln   = uh + 2097152;                   // 524288 bf16 (LN1 rows)

    void* kargs[] = {
        (void*)&c_atom, (void*)&p_lm, (void*)&p_idx, (void*)&tok,
        (void*)&ln_a_g, (void*)&ln_a_b,
        (void*)&w_q, (void*)&w_k, (void*)&w_v, (void*)&w_g, (void*)&w_o,
        (void*)&pb_w, (void*)&pb_b, (void*)&ln_f_g, (void*)&ln_f_b,
        (void*)&sw_w1, (void*)&sw_w2, (void*)&sw_w3, (void*)&tok_w, (void*)&tok_b,
        (void*)&out,
        (void*)&cnt, (void*)&tst, (void*)&win,
        (void*)&pqkvg, (void*)&pwo, (void*)&pw12, (void*)&pw3, (void*)&ptok,
        (void*)&hln, (void*)&atth, (void*)&qbuf, (void*)&qkvg, (void*)&uh };

    hipLaunchCooperativeKernel((const void*)mega, dim3(256), dim3(512),
                               kargs, 0, stream);
}

// Round 4
// 306.562 us; speedup vs baseline: 1.0913x; 1.0913x over previous
//
#include <hip/hip_runtime.h>
#include <hip/hip_bf16.h>
#include <math.h>

// Problem constants (fixed by setup_inputs)
#define B_     2
#define N_     2048
#define DA     128
#define H_     4
#define DH     32
#define DFF    512
#define DM     512
#define NT     512
#define NP     16384
#define MAXL   32    // max atoms per token group (validated in prior session)
#define LDSP   136   // padded LDS row stride (shorts): 2-way bank aliasing only
#define NBLK   256   // persistent blocks == CU count (co-residency by capacity)

typedef short bf16x8 __attribute__((ext_vector_type(8)));   // 8 bf16 in 4 VGPRs
typedef float f32x4  __attribute__((ext_vector_type(4)));   // MFMA accumulator

__device__ __forceinline__ short bf16r(float x) {           // RNE fp32->bf16
    union { float f; unsigned u; } v; v.f = x;
    unsigned r = v.u + 0x7FFFu + ((v.u >> 16) & 1u);
    return (short)(r >> 16);
}
__device__ __forceinline__ float bf2f(short h) {
    union { unsigned u; float f; } v;
    v.u = ((unsigned)(unsigned short)h) << 16;
    return v.f;
}

// ---- lightweight grid barrier (replaces cg::grid.sync) ----------------------
// One atomicAdd per block; spin on acquire-load; __threadfence for cross-XCD
// L2 writeback/invalidate. Per-phase counter (no generation/sense needed).
__device__ __forceinline__ void gridbar(int* __restrict__ bar, int phase) {
    __syncthreads();                       // all waves' stores drained (vmcnt 0)
    if (threadIdx.x == 0) {
        __threadfence();                   // release: agent-scope L2 writeback
        __hip_atomic_fetch_add(&bar[phase], 1, __ATOMIC_RELEASE,
                               __HIP_MEMORY_SCOPE_AGENT);
        while (__hip_atomic_load(&bar[phase], __ATOMIC_ACQUIRE,
                                 __HIP_MEMORY_SCOPE_AGENT) < NBLK) {
            __builtin_amdgcn_s_sleep(2);
        }
        __threadfence();                   // acquire: invalidate stale lines
    }
    __syncthreads();
}

// -------- MFMA GEMM cores ----------------------------------------------------
template<int K, int NTT>
__device__ __forceinline__ void gemm_lds(const short* __restrict__ Alds,
                                         const short* __restrict__ Bp,
                                         int nt0, int lane, f32x4* acc) {
    constexpr int KT = K / 32;
    const short* arow = Alds + (lane & 15) * LDSP + (lane >> 4) * 8;
    const short* bbase = Bp + nt0 * KT * 512 + lane * 8;
#pragma unroll
    for (int kt = 0; kt < KT; kt++) {
        bf16x8 a = *(const bf16x8*)(arow + kt * 32);
#pragma unroll
        for (int nt = 0; nt < NTT; nt++) {
            bf16x8 b = *(const bf16x8*)(bbase + (nt * KT + kt) * 512);
            acc[nt] = __builtin_amdgcn_mfma_f32_16x16x32_bf16(a, b, acc[nt], 0, 0, 0);
        }
    }
}

template<int K, int NTT>
__device__ __forceinline__ void gemm_glb(const short* __restrict__ A,
                                         const short* __restrict__ Bp,
                                         int m0, int nt0, int lane, f32x4* acc) {
    constexpr int KT = K / 32;
    const short* arow = A + (m0 + (lane & 15)) * K + (lane >> 4) * 8;
    const short* bbase = Bp + nt0 * KT * 512 + lane * 8;
#pragma unroll
    for (int kt = 0; kt < KT; kt++) {
        bf16x8 a = *(const bf16x8*)(arow + kt * 32);
#pragma unroll
        for (int nt = 0; nt < NTT; nt++) {
            bf16x8 b = *(const bf16x8*)(bbase + (nt * KT + kt) * 512);
            acc[nt] = __builtin_amdgcn_mfma_f32_16x16x32_bf16(a, b, acc[nt], 0, 0, 0);
        }
    }
}

// =============================================================================
// Single persistent kernel: 256 blocks x 512 threads (1 block/CU by capacity).
// Phases separated by the lightweight gridbar (5 barriers).
// =============================================================================
__global__ __launch_bounds__(512, 2) void mega(
        const float* __restrict__ c_atom, const float* __restrict__ plm,
        const int* __restrict__ pidx, const int* __restrict__ tok,
        const float* __restrict__ lnag, const float* __restrict__ lnab,
        const float* __restrict__ wq, const float* __restrict__ wk,
        const float* __restrict__ wv, const float* __restrict__ wg,
        const float* __restrict__ wo,
        const float* __restrict__ pbw, const float* __restrict__ pbb,
        const float* __restrict__ lnfg, const float* __restrict__ lnfb,
        const float* __restrict__ w1, const float* __restrict__ w2,
        const float* __restrict__ w3, const float* __restrict__ tw,
        const float* __restrict__ tb,
        float* __restrict__ out,
        int* __restrict__ cnt, int* __restrict__ tst, int* __restrict__ win,
        short* __restrict__ pqkvg, short* __restrict__ pwo,
        short* __restrict__ pw12, short* __restrict__ pw3,
        short* __restrict__ ptok,
        short* __restrict__ hln, short* __restrict__ atth,
        float* __restrict__ qbuf, float* __restrict__ qkvg,
        short* __restrict__ uh, int* __restrict__ bar) {
    __shared__ __align__(16) char smraw[128 * LDSP * 2];   // 34816 B, phase-reused
    int blk = blockIdx.x;
    int tid = threadIdx.x;
    int lane = tid & 63, wave = tid >> 6;

    // ================= P0: weight pack + LN1 + hist/scan + pair winners ======
    if (blk < 84) {
        // weight pack: wave w of block b handles group g = b*8+w  (672 groups)
        int g = blk * 8 + wave;
        int quad = lane >> 4, nn = lane & 15;
        const float* src; short* dst; int stride;
        if (g < 128) {                   // Wqkvg: K=128, N=512, KT=4
            int kt = g & 3, nt = g >> 2;
            int n = nt * 16 + nn;
            const float* w = (n < 128) ? wq : (n < 256) ? wk : (n < 384) ? wv : wg;
            src = w + (kt * 32 + quad * 8) * 128 + (n & 127);
            dst = pqkvg + (g * 64 + lane) * 8;
            stride = 128;
        } else if (g < 160) {            // Wo: K=128, N=128
            int gg = g - 128; int kt = gg & 3, nt = gg >> 2;
            src = wo + (kt * 32 + quad * 8) * 128 + nt * 16 + nn;
            dst = pwo + (gg * 64 + lane) * 8;
            stride = 128;
        } else if (g < 416) {            // W12 interleaved: K=128, Npacked=1024
            int gg = g - 160; int kt = gg & 3, nt = gg >> 2;
            int n = nt * 16 + nn;        // even=w1, odd=w2, real col n>>1
            src = ((n & 1) ? w2 : w1) + (kt * 32 + quad * 8) * 512 + (n >> 1);
            dst = pw12 + (gg * 64 + lane) * 8;
            stride = 512;
        } else if (g < 544) {            // W3: K=512, N=128, KT=16
            int gg = g - 416; int kt = gg & 15, nt = gg >> 4;
            src = w3 + (kt * 32 + quad * 8) * 128 + nt * 16 + nn;
            dst = pw3 + (gg * 64 + lane) * 8;
            stride = 128;
        } else {                         // Wtok: K=128, N=512
            int gg = g - 544; int kt = gg & 3, nt = gg >> 2;
            src = tw + (kt * 32 + quad * 8) * 512 + nt * 16 + nn;
            dst = ptok + (gg * 64 + lane) * 8;
            stride = 512;
        }
#pragma unroll
        for (int j = 0; j < 8; j++) dst[j] = bf16r(src[j * stride]);
    } else if (blk < 116) {
        // LN1: 128 rows/block (4 thr/row, 32 cols each) -> bf16 hln
        int rowg = (blk - 84) * 128 + (tid >> 2);       // 0..4095
        int sub = tid & 3;
        const float* xr = c_atom + rowg * DA + sub * 32;
        float4 v[8];
        float s = 0.f, sq = 0.f;
#pragma unroll
        for (int i = 0; i < 8; i++) {
            v[i] = *(const float4*)(xr + i * 4);
            s  += v[i].x + v[i].y + v[i].z + v[i].w;
            sq += v[i].x * v[i].x + v[i].y * v[i].y + v[i].z * v[i].z + v[i].w * v[i].w;
        }
        s += __shfl_xor(s, 1); sq += __shfl_xor(sq, 1);
        s += __shfl_xor(s, 2); sq += __shfl_xor(sq, 2);
        float mean = s * (1.f / 128.f);
        float var = sq * (1.f / 128.f) - mean * mean;
        float inv = rsqrtf(var + 1e-5f);
        const float* gp = lnag + sub * 32;
        const float* bp = lnab + sub * 32;
        short* dst = hln + rowg * DA + sub * 32;
#pragma unroll
        for (int i = 0; i < 8; i++) {
            dst[i * 4 + 0] = bf16r((v[i].x - mean) * inv * gp[i * 4 + 0] + bp[i * 4 + 0]);
            dst[i * 4 + 1] = bf16r((v[i].y - mean) * inv * gp[i * 4 + 1] + bp[i * 4 + 1]);
            dst[i * 4 + 2] = bf16r((v[i].z - mean) * inv * gp[i * 4 + 2] + bp[i * 4 + 2]);
            dst[i * 4 + 3] = bf16r((v[i].w - mean) * inv * gp[i * 4 + 3] + bp[i * 4 + 3]);
        }
    } else if (blk == 116) {
        // histogram + segmented exclusive scan (1024 entries, 512 threads)
        int* c  = (int*)smraw;
        int* sb = c + 1024;
        c[tid] = 0; c[tid + 512] = 0;
        __syncthreads();
#pragma unroll
        for (int i = 0; i < 8; i++) {
            int idx = tid + i * 512;            // 0..4095
            int b = idx >> 11;
            atomicAdd(&c[b * NT + tok[idx]], 1);
        }
        __syncthreads();
        int v0 = c[tid], v1 = c[tid + 512];
        int* cur = c;
        int* alt = sb;
        for (int d = 1; d < 512; d <<= 1) {
            int y0 = cur[tid];       if (tid >= d) y0 += cur[tid - d];
            int y1 = cur[tid + 512]; if (tid >= d) y1 += cur[tid + 512 - d];
            alt[tid] = y0; alt[tid + 512] = y1;
            __syncthreads();
            int* t_ = cur; cur = alt; alt = t_;
        }
        tst[tid] = cur[tid] - v0;          cnt[tid] = v0;
        tst[tid + 512] = cur[tid + 512] - v1; cnt[tid + 512] = v1;
    } else if (blk < 133) {
        // pair winners: 2048 pairs/block; poison (0xAA.. < 0) = no winner
        int base = (blk - 117) * 2048;
#pragma unroll
        for (int i = 0; i < 4; i++) {
            int p = base + i * 512 + tid;       // 0..32767
            int b = p >> 14, pp = p & (NP - 1);
            int src = pidx[p * 2], dst = pidx[p * 2 + 1];
            if (tok[b * N_ + src] == tok[b * N_ + dst])
                atomicMax(&win[(b * N_ + src) * MAXL + (dst & 31)], pp + 1);
        }
    }
    gridbar(bar, 0);

    // ================= P1: qkvg = hln @ [wq|wk|wv|wg]  (fp32 out) ============
    {
        int xb = blk & 63, yb = blk >> 6;          // 64-row block, 128-col block
        int m0 = xb * 64 + (wave & 3) * 16;
        int nt0 = yb * 8 + (wave >> 2) * 4;
        f32x4 acc[4];
#pragma unroll
        for (int i = 0; i < 4; i++)
#pragma unroll
            for (int r = 0; r < 4; r++) acc[i][r] = 0.f;
        gemm_glb<128, 4>(hln, pqkvg, m0, nt0, lane, acc);
        int r0 = m0 + ((lane >> 4) << 2);
        int cc = lane & 15;
#pragma unroll
        for (int nt = 0; nt < 4; nt++) {
            int col = (nt0 + nt) * 16 + cc;
#pragma unroll
            for (int r = 0; r < 4; r++) qkvg[(r0 + r) * 512 + col] = acc[nt][r];
        }
    }
    gridbar(bar, 1);

    // ================= P2: grouped attention, online softmax, in-register ====
    {
        int team = tid >> 7;                      // 4 teams of 128 threads
        int t127 = tid & 127;
        int h = t127 >> 5, d = t127 & 31;
        const float scale = 0.17677669529663687f; // 1/sqrt(32)
        for (int i = 0; i < 4; i++) {
            int atom = blk * 16 + team * 4 + i;   // 0..4095 (contiguous/team)
            int b = atom >> 11;
            int t = tok[atom];
            int start = tst[b * NT + t];
            int L = cnt[b * NT + t];
            if (L > MAXL) L = MAXL;
            float qv = qkvg[atom * 512 + h * DH + d];
            const float* kbase = qkvg + (size_t)(b * N_ + start) * 512 + 128 + h * DH + d;
            const float* vbase = kbase + 128;
            const int* wbase = win + atom * MAXL;
            float mrun = -1e30f, denom = 0.f, acc = 0.f;
            for (int j0 = 0; j0 < L; j0 += 8) {
                int m8 = L - j0; if (m8 > 8) m8 = 8;
                float kv[8], vv[8]; int pw[8];
#pragma unroll
                for (int u = 0; u < 8; u++) {
                    if (u < m8) {
                        kv[u] = kbase[(j0 + u) * 512];
                        vv[u] = vbase[(j0 + u) * 512];
                        pw[u] = wbase[(start + j0 + u) & 31];
                    }
                }
                float s[8];
#pragma unroll
                for (int u = 0; u < 8; u++) {
                    if (u < m8) {
                        float sv = qv * kv[u];
#pragma unroll
                        for (int mm = 16; mm; mm >>= 1) sv += __shfl_xor(sv, mm, 32);
                        sv *= scale;
                        if (pw[u] > 0) {          // inline bias from winning pair
                            const float* pl = plm + (size_t)(b * NP + pw[u] - 1) * 16;
                            float bsum = pbb[h];
#pragma unroll
                            for (int f = 0; f < 16; f++) bsum += pl[f] * pbw[f * H_ + h];
                            sv += bsum;
                        }
                        s[u] = sv;
                    }
                }
                float cmax = -1e30f;
#pragma unroll
                for (int u = 0; u < 8; u++)
                    if (u < m8) cmax = fmaxf(cmax, s[u]);
                float mnew = fmaxf(mrun, cmax);
                float rs = expf(mrun - mnew);     // first iter: exp(-inf)=0
                denom *= rs; acc *= rs;
#pragma unroll
                for (int u = 0; u < 8; u++) {
                    if (u < m8) {
                        float p = expf(s[u] - mnew);
                        denom += p;
                        acc += p * vv[u];
                    }
                }
                mrun = mnew;
            }
            atth[atom * DA + h * DH + d] = bf16r(acc / denom);
        }
    }
    gridbar(bar, 2);

    // ================= P3: outproj + gate/residual + LN2 + ffn1 ==============
    {
        short* alds = (short*)smraw;              // 128 x LDSP bf16
        int xb = blk & 31, yb = blk >> 5;         // 128-row block, col-eighth
        int m0 = xb * 128 + wave * 16;
        int quad = lane >> 4, cc = lane & 15;
        f32x4 acc[8];
#pragma unroll
        for (int i = 0; i < 8; i++)
#pragma unroll
            for (int r = 0; r < 4; r++) acc[i][r] = 0.f;
        gemm_glb<128, 8>(atth, pwo, m0, 0, lane, acc);
        float rsum[4], rsq[4];
#pragma unroll
        for (int r = 0; r < 4; r++) {
            int row = m0 + quad * 4 + r;
            float s = 0.f, sq = 0.f;
#pragma unroll
            for (int nt = 0; nt < 8; nt++) {
                int col = nt * 16 + cc;
                float g = qkvg[row * 512 + 384 + col];
                float sg = 1.f / (1.f + expf(-g));
                float val = c_atom[row * DA + col] + sg * acc[nt][r];
                acc[nt][r] = val;
                s += val; sq += val * val;
                if (yb == 0) qbuf[row * DA + col] = val;
            }
            rsum[r] = s; rsq[r] = sq;
        }
#pragma unroll
        for (int m = 1; m < 16; m <<= 1) {
#pragma unroll
            for (int r = 0; r < 4; r++) {
                rsum[r] += __shfl_xor(rsum[r], m);
                rsq[r]  += __shfl_xor(rsq[r], m);
            }
        }
#pragma unroll
        for (int r = 0; r < 4; r++) {
            float mean = rsum[r] * (1.f / 128.f);
            float var = rsq[r] * (1.f / 128.f) - mean * mean;
            float inv = rsqrtf(var + 1e-5f);
            int lrow = wave * 16 + quad * 4 + r;
#pragma unroll
            for (int nt = 0; nt < 8; nt++) {
                int col = nt * 16 + cc;
                alds[lrow * LDSP + col] = bf16r((acc[nt][r] - mean) * inv * lnfg[col] + lnfb[col]);
            }
        }
        __syncthreads();
        // ffn1: u = bf16( silu(h@w1) * (h@w2) ), packed tiles nt0..nt0+7
        int nt0 = yb * 8;
        f32x4 acc2[8];
#pragma unroll
        for (int i = 0; i < 8; i++)
#pragma unroll
            for (int r = 0; r < 4; r++) acc2[i][r] = 0.f;
        gemm_lds<128, 8>(alds + wave * 16 * LDSP, pw12, nt0, lane, acc2);
        int r0 = m0 + quad * 4;
#pragma unroll
        for (int nt = 0; nt < 8; nt++) {
            int col8 = (nt0 + nt) * 8 + (cc >> 1);    // real u column
#pragma unroll
            for (int r = 0; r < 4; r++) {
                float v = acc2[nt][r];
                float p = __shfl_xor(v, 1);           // partner (w2) value
                if (!(lane & 1)) {                    // even lane holds w1 result
                    float sil = v / (1.f + expf(-v));
                    uh[(r0 + r) * DFF + col8] = bf16r(sil * p);
                }
            }
        }
    }
    gridbar(bar, 3);

    // ================= P4: q2 = bf16(qbuf + u @ w3)   (K=512) ================
    {
        short* q2h = atth;                        // atth dead; reuse as q2h
        int m0 = blk * 16;
        int nt0 = wave;                           // 8 col tiles of 16
        f32x4 acc[1];
#pragma unroll
        for (int r = 0; r < 4; r++) acc[0][r] = 0.f;
        gemm_glb<512, 1>(uh, pw3, m0, nt0, lane, acc);
        int r0 = m0 + ((lane >> 4) << 2);
        int cc = lane & 15;
        int col = nt0 * 16 + cc;
#pragma unroll
        for (int r = 0; r < 4; r++) {
            int row = r0 + r;
            q2h[row * DA + col] = bf16r(qbuf[row * DA + col] + acc[0][r]);
        }
    }
    gridbar(bar, 4);

    // ================= P5: segment-mean + token projection ===================
    {
        const short* q2h = atth;
        short* alds = (short*)smraw;              // 64 x LDSP bf16
        int xb = blk & 15, yb = blk >> 4;         // 64-token block, 32-col block
        int tt = tid >> 3, sub = tid & 7;         // 8 thr/token, 16 cols each
        int token = xb * 64 + tt;                 // linear (b*NT + t)
        int start = tst[token], n = cnt[token];
        int b = token >> 9;
        float accm[16];
#pragma unroll
        for (int i = 0; i < 16; i++) accm[i] = 0.f;
        const short* rp = q2h + (size_t)(b * N_ + start) * DA + sub * 16;
        for (int a = 0; a < n; a++) {
            bf16x8 v0 = *(const bf16x8*)(rp + a * DA);
            bf16x8 v1 = *(const bf16x8*)(rp + a * DA + 8);
#pragma unroll
            for (int j = 0; j < 8; j++) {
                accm[j]     += bf2f(v0[j]);
                accm[8 + j] += bf2f(v1[j]);
            }
        }
        float inv = (n > 0) ? 1.f / (float)n : 0.f;
        short* dst = alds + tt * LDSP + sub * 16;
#pragma unroll
        for (int i = 0; i < 16; i++) dst[i] = bf16r(accm[i] * inv);
        __syncthreads();

        int nt0 = yb * 2 + (wave >> 2);           // 32 col tiles of 16 total
        f32x4 acc[1];
#pragma unroll
        for (int r = 0; r < 4; r++) acc[0][r] = 0.f;
        gemm_lds<128, 1>(alds + (wave & 3) * 16 * LDSP, ptok, nt0, lane, acc);
        int r0 = xb * 64 + (wave & 3) * 16 + ((lane >> 4) << 2);
        int cc = lane & 15;
        int col = nt0 * 16 + cc;
        float bv = tb[col];
#pragma unroll
        for (int r = 0; r < 4; r++)
            out[(size_t)(r0 + r) * DM + col] = acc[0][r] + bv;
    }
}

extern "C" void kernel_launch(void* const* d_in, const int* in_sizes, int n_in,
                              void* d_out, int out_size, void* d_ws, size_t ws_size,
                              hipStream_t stream) {
    const float* c_atom  = (const float*)d_in[0];
    const float* p_lm    = (const float*)d_in[1];
    const int*   p_idx   = (const int*)d_in[2];
    const int*   tok     = (const int*)d_in[3];
    // d_in[4] = n_tokens (512, hardcoded)
    const float* ln_a_g  = (const float*)d_in[5];
    const float* ln_a_b  = (const float*)d_in[6];
    const float* w_q     = (const float*)d_in[7];
    const float* w_k     = (const float*)d_in[8];
    const float* w_v     = (const float*)d_in[9];
    const float* w_g     = (const float*)d_in[10];
    const float* w_o     = (const float*)d_in[11];
    const float* pb_w    = (const float*)d_in[12];
    const float* pb_b    = (const float*)d_in[13];
    const float* ln_f_g  = (const float*)d_in[14];
    const float* ln_f_b  = (const float*)d_in[15];
    const float* sw_w1   = (const float*)d_in[16];
    const float* sw_w2   = (const float*)d_in[17];
    const float* sw_w3   = (const float*)d_in[18];
    const float* tok_w   = (const float*)d_in[19];
    const float* tok_b   = (const float*)d_in[20];
    float* out = (float*)d_out;

    // ---------------- workspace layout (no aliasing hazards) -----------------
    float* ws = (float*)d_ws;
    int*   cnt   = (int*)ws;                       // 1024 i
    int*   tst   = cnt + 1024;                     // 1024 i
    int*   win   = tst + 1024;                     // 131072 i (poison = no winner)
    short* pqkvg = (short*)(win + 131072);         // 65536 bf16
    short* pwo   = pqkvg + 65536;                  // 16384 bf16
    short* pw12  = pwo + 16384;                    // 131072 bf16
    short* pw3   = pw12 + 131072;                  // 65536 bf16
    short* ptok  = pw3 + 65536;                    // 65536 bf16
    short* atth  = ptok + 65536;                   // 524288 bf16 [reused as q2h]
    float* qbuf  = (float*)(atth + 524288);        // 524288 f
    float* qkvg  = qbuf + 524288;                  // 2097152 f
    short* uh    = (short*)(qkvg + 2097152);       // 2097152 bf16
    short* hln   = uh + 2097152;                   // 524288 bf16 (LN1 rows)
    int*   bar   = (int*)(hln + 524288);           // 16 i barrier counters

    hipMemsetAsync(bar, 0, 64, stream);            // zero barrier counters

    mega<<<dim3(NBLK), dim3(512), 0, stream>>>(
        c_atom, p_lm, p_idx, tok, ln_a_g, ln_a_b,
        w_q, w_k, w_v, w_g, w_o, pb_w, pb_b, ln_f_g, ln_f_b,
        sw_w1, sw_w2, sw_w3, tok_w, tok_b, out,
        cnt, tst, win, pqkvg, pwo, pw12, pw3, ptok,
        hln, atth, qbuf, qkvg, uh, bar);
}

// Round 5
// 212.761 us; speedup vs baseline: 1.5724x; 1.4409x over previous
//
#include <hip/hip_runtime.h>
#include <hip/hip_bf16.h>
#include <math.h>

// Problem constants (fixed by setup_inputs)
#define B_     2
#define N_     2048
#define DA     128
#define H_     4
#define DH     32
#define DFF    512
#define DM     512
#define NT     512
#define NP     16384
#define MAXL   32    // max atoms per token group (validated in prior session)
#define LDSP   136   // padded LDS row stride (shorts) for GEMM-A tiles

typedef short bf16x8 __attribute__((ext_vector_type(8)));   // 8 bf16 in 4 VGPRs
typedef float f32x4  __attribute__((ext_vector_type(4)));   // MFMA accumulator

__device__ __forceinline__ short bf16r(float x) {           // RNE fp32->bf16
    union { float f; unsigned u; } v; v.f = x;
    unsigned r = v.u + 0x7FFFu + ((v.u >> 16) & 1u);
    return (short)(r >> 16);
}
__device__ __forceinline__ float bf2f(short h) {
    union { unsigned u; float f; } v;
    v.u = ((unsigned)(unsigned short)h) << 16;
    return v.f;
}

// ------- setup: weight pack (blk 0-41) + hist/scan (blk 42) + pair_win (43-74)
//         + LN1 -> bf16 hln (blk 75-90, 256 rows each)   [verified r0/r2]
__global__ __launch_bounds__(1024) void setup_kernel(
        const float* __restrict__ wq, const float* __restrict__ wk,
        const float* __restrict__ wv, const float* __restrict__ wg,
        const float* __restrict__ wo, const float* __restrict__ w1,
        const float* __restrict__ w2, const float* __restrict__ w3,
        const float* __restrict__ tw, const int* __restrict__ tok,
        const int* __restrict__ pidx,
        const float* __restrict__ c_atom, const float* __restrict__ lng,
        const float* __restrict__ lnb,
        short* __restrict__ pqkvg, short* __restrict__ pwo,
        short* __restrict__ pw12, short* __restrict__ pw3,
        short* __restrict__ ptok, short* __restrict__ hln,
        int* __restrict__ cnt, int* __restrict__ tst,
        int* __restrict__ win) {
    __shared__ int c[1024];
    __shared__ int sb[1024];
    if (blockIdx.x < 42) {
        int gid = blockIdx.x * 1024 + threadIdx.x;   // 0..43007
        int lane = gid & 63;
        int grp = gid >> 6;                          // 0..671
        int quad = lane >> 4, nn = lane & 15;
        const float* src; short* dst; int stride;
        if (grp < 128) {                 // Wqkvg: K=128, N=512 (wq|wk|wv|wg), KT=4
            int g = grp; int kt = g & 3, nt = g >> 2;
            int n = nt * 16 + nn;
            const float* w = (n < 128) ? wq : (n < 256) ? wk : (n < 384) ? wv : wg;
            src = w + (kt * 32 + quad * 8) * 128 + (n & 127);
            dst = pqkvg + (g * 64 + lane) * 8;
            stride = 128;
        } else if (grp < 160) {          // Wo: K=128, N=128, KT=4
            int g = grp - 128; int kt = g & 3, nt = g >> 2;
            src = wo + (kt * 32 + quad * 8) * 128 + nt * 16 + nn;
            dst = pwo + (g * 64 + lane) * 8;
            stride = 128;
        } else if (grp < 416) {          // W12 interleaved: K=128, Npacked=1024, KT=4
            int g = grp - 160; int kt = g & 3, nt = g >> 2;
            int n = nt * 16 + nn;        // even=w1, odd=w2, real col n>>1
            src = ((n & 1) ? w2 : w1) + (kt * 32 + quad * 8) * 512 + (n >> 1);
            dst = pw12 + (g * 64 + lane) * 8;
            stride = 512;
        } else if (grp < 544) {          // W3: K=512, N=128, KT=16
            int g = grp - 416; int kt = g & 15, nt = g >> 4;
            src = w3 + (kt * 32 + quad * 8) * 128 + nt * 16 + nn;
            dst = pw3 + (g * 64 + lane) * 8;
            stride = 128;
        } else {                         // Wtok: K=128, N=512, KT=4
            int g = grp - 544; int kt = g & 3, nt = g >> 2;
            src = tw + (kt * 32 + quad * 8) * 512 + nt * 16 + nn;
            dst = ptok + (g * 64 + lane) * 8;
            stride = 512;
        }
#pragma unroll
        for (int j = 0; j < 8; j++) dst[j] = bf16r(src[j * stride]);
    } else if (blockIdx.x == 42) {
        // histogram + segmented exclusive scan over token counts
        int tid = threadIdx.x;
        c[tid] = 0;
        __syncthreads();
#pragma unroll
        for (int i = 0; i < 4; i++) {
            int idx = tid + i * 1024;           // 0..4095
            int b = idx >> 11;
            atomicAdd(&c[b * NT + tok[idx]], 1);
        }
        __syncthreads();
        int t = tid & (NT - 1);
        int v = c[tid];
        int* cur = c;
        int* alt = sb;
        for (int d = 1; d < NT; d <<= 1) {
            int y = cur[tid];
            if (t >= d) y += cur[tid - d];
            alt[tid] = y;
            __syncthreads();
            int* tmp = cur; cur = alt; alt = tmp;
        }
        tst[tid] = cur[tid] - v;   // exclusive prefix (within batch)
        cnt[tid] = v;
    } else if (blockIdx.x < 75) {
        // pair winner: key by dst&31 (unique within <=32-atom contiguous group);
        // store pp+1 via atomicMax over 0xAA poison (<0) -> no memset needed.
        int p = (blockIdx.x - 43) * 1024 + threadIdx.x;   // 0..32767
        int b = p >> 14, pp = p & (NP - 1);
        int src = pidx[p * 2], dst = pidx[p * 2 + 1];
        if (tok[b * N_ + src] == tok[b * N_ + dst])
            atomicMax(&win[(b * N_ + src) * MAXL + (dst & 31)], pp + 1);
    } else {
        // LN1: 256 rows per block (4 threads/row, 32 cols each) -> bf16 hln
        int t = threadIdx.x;
        int rowg = (blockIdx.x - 75) * 256 + (t >> 2);   // 0..4095
        int sub = t & 3;
        const float* xr = c_atom + rowg * DA + sub * 32;
        float4 v[8];
        float s = 0.f, sq = 0.f;
#pragma unroll
        for (int i = 0; i < 8; i++) {
            v[i] = *(const float4*)(xr + i * 4);
            s  += v[i].x + v[i].y + v[i].z + v[i].w;
            sq += v[i].x * v[i].x + v[i].y * v[i].y + v[i].z * v[i].z + v[i].w * v[i].w;
        }
        s += __shfl_xor(s, 1); sq += __shfl_xor(sq, 1);
        s += __shfl_xor(s, 2); sq += __shfl_xor(sq, 2);
        float mean = s * (1.f / 128.f);
        float var = sq * (1.f / 128.f) - mean * mean;
        float inv = rsqrtf(var + 1e-5f);
        const float* gp = lng + sub * 32;
        const float* bp = lnb + sub * 32;
        short* dst = hln + rowg * DA + sub * 32;
#pragma unroll
        for (int i = 0; i < 8; i++) {
            dst[i * 4 + 0] = bf16r((v[i].x - mean) * inv * gp[i * 4 + 0] + bp[i * 4 + 0]);
            dst[i * 4 + 1] = bf16r((v[i].y - mean) * inv * gp[i * 4 + 1] + bp[i * 4 + 1]);
            dst[i * 4 + 2] = bf16r((v[i].z - mean) * inv * gp[i * 4 + 2] + bp[i * 4 + 2]);
            dst[i * 4 + 3] = bf16r((v[i].w - mean) * inv * gp[i * 4 + 3] + bp[i * 4 + 3]);
        }
    }
}

// -------- generic MFMA GEMM core: A from LDS (stride STR), B packed ----------
// A-frag: row=lane&15 (+row-tile offset in Abase), k=(lane>>4)*8 + kt*32.
// B-frag: (nt*KTB + kt)*512 + lane*8.  C: row=quad*4+r, col=lane&15. [verified]
template<int KT, int KTB, int NTT, int STR>
__device__ __forceinline__ void gemm_a(const short* __restrict__ Abase,
                                       const short* __restrict__ Bp,
                                       int nt0, int lane, f32x4* acc) {
    const short* arow = Abase + (lane & 15) * STR + (lane >> 4) * 8;
    const short* bbase = Bp + lane * 8;
#pragma unroll
    for (int kt = 0; kt < KT; kt++) {
        bf16x8 a = *(const bf16x8*)(arow + kt * 32);
#pragma unroll
        for (int nt = 0; nt < NTT; nt++) {
            bf16x8 b = *(const bf16x8*)(bbase + ((nt0 + nt) * KTB + kt) * 512);
            acc[nt] = __builtin_amdgcn_mfma_f32_16x16x32_bf16(a, b, acc[nt], 0, 0, 0);
        }
    }
}

// =============================================================================
// tokfused: one block per token group (<=32 contiguous atoms). Entire post-LN1
// pipeline in LDS/registers: QKVG -> attn -> outproj+gate+res -> LN2 -> ffn1
// -> ffn2+res -> segment mean -> token projection. 1024 blocks x 256 thr.
// =============================================================================
// LDS arena (49664 B): [Q 8192][K 8192][A 8704][V 8192][sg 16384]
//   overlays: val(f32,16K)->Q+K ; h(bf16,s136)->A ; u(bf16,s264,16.9K)->V+sg ;
//             q2(bf16,s128)->Q ; meanrow(bf16,s136)->K
__global__ __launch_bounds__(256, 2) void tokfused(
        const short* __restrict__ hln, const float* __restrict__ c_atom,
        const float* __restrict__ plm,
        const int* __restrict__ tst, const int* __restrict__ cnt,
        const int* __restrict__ win,
        const short* __restrict__ pqkvg, const short* __restrict__ pwo,
        const short* __restrict__ pw12, const short* __restrict__ pw3,
        const short* __restrict__ ptok,
        const float* __restrict__ pbw, const float* __restrict__ pbb,
        const float* __restrict__ lnfg, const float* __restrict__ lnfb,
        const float* __restrict__ tb, float* __restrict__ out) {
    __shared__ __align__(16) char arena[49664];
    short* Qs  = (short*)(arena + 0);        // 32x128 bf16
    short* Ks  = (short*)(arena + 8192);     // 32x128 bf16
    short* As  = (short*)(arena + 16384);    // 32x136 bf16 (A-stage/att_out/h)
    short* Vs  = (short*)(arena + 25088);    // 32x128 bf16
    float* sgf = (float*)(arena + 33280);    // 32x128 f32 sigmoid(G)
    float* valf = (float*)(arena + 0);       // 32x128 f32  (over Q+K)
    short* us   = (short*)(arena + 25088);   // 32x264 bf16 u-chunk (over V+sg)
    short* q2s  = (short*)(arena + 0);       // 32x128 bf16 (over Q)
    short* mrs  = (short*)(arena + 8192);    // 16x136 bf16 mean tile (over K)

    int token = blockIdx.x;                  // b*NT + t
    int b = token >> 9;
    int tid = threadIdx.x;
    int lane = tid & 63, wave = tid >> 6;
    int quad = lane >> 4, cc = lane & 15;
    int start = tst[token];
    int L = cnt[token]; if (L > MAXL) L = MAXL;

    // ---- S0: stage hln rows (zeros beyond L) --------------------------------
    {
        int row = tid >> 3, sub = tid & 7;       // 32 rows x 8 chunks of 16
        int4 v0 = {0,0,0,0}, v1 = {0,0,0,0};
        if (row < L) {
            const int4* src = (const int4*)(hln + (size_t)(b * N_ + start + row) * DA + sub * 16);
            v0 = src[0]; v1 = src[1];
        }
        int4* dst = (int4*)(As + row * LDSP + sub * 16);
        dst[0] = v0; dst[1] = v1;
    }
    __syncthreads();

    // ---- S1: QKVG = A(32x128) @ pqkvg(128x512); Q/K/V bf16, sg=sigmoid(G) ---
    {
        f32x4 a0[8], a1[8];
#pragma unroll
        for (int i = 0; i < 8; i++)
#pragma unroll
            for (int r = 0; r < 4; r++) { a0[i][r] = 0.f; a1[i][r] = 0.f; }
        gemm_a<4, 4, 8, LDSP>(As, pqkvg, wave * 8, lane, a0);
        gemm_a<4, 4, 8, LDSP>(As + 16 * LDSP, pqkvg, wave * 8, lane, a1);
#pragma unroll
        for (int rt = 0; rt < 2; rt++) {
            f32x4* ac = rt ? a1 : a0;
#pragma unroll
            for (int nt = 0; nt < 8; nt++) {
                int gcol = wave * 128 + nt * 16 + cc;
                int seg = gcol >> 7, lc = gcol & 127;
#pragma unroll
                for (int r = 0; r < 4; r++) {
                    int lrow = rt * 16 + quad * 4 + r;
                    float v = ac[nt][r];
                    if (seg == 3) sgf[lrow * 128 + lc] = 1.f / (1.f + expf(-v));
                    else {
                        short* dst = (seg == 0) ? Qs : (seg == 1) ? Ks : Vs;
                        dst[lrow * 128 + lc] = bf16r(v);
                    }
                }
            }
        }
    }
    __syncthreads();

    // ---- S2: attention (K/V in LDS), online softmax, inline pair bias -------
    {
        int slot = tid >> 7;                  // 2 atoms processed in parallel
        int t127 = tid & 127;
        int h = t127 >> 5, d = t127 & 31;
        const float scale = 0.17677669529663687f;   // 1/sqrt(32)
        for (int i = slot; i < L; i += 2) {
            float qv = bf2f(Qs[i * 128 + h * DH + d]);
            const int* wrow = win + (size_t)(b * N_ + start + i) * MAXL;
            float mrun = -1e30f, denom = 0.f, acc = 0.f;
            for (int j = 0; j < L; j++) {
                float kv = bf2f(Ks[j * 128 + h * DH + d]);
                float s = qv * kv;
#pragma unroll
                for (int mm = 16; mm; mm >>= 1) s += __shfl_xor(s, mm, 32);
                s *= scale;
                int pwv = wrow[(start + j) & 31];
                if (pwv > 0) {                // rare: winning pair bias
                    const float* pl = plm + (size_t)(b * NP + pwv - 1) * 16;
                    float bsum = pbb[h];
#pragma unroll
                    for (int f = 0; f < 16; f++) bsum += pl[f] * pbw[f * H_ + h];
                    s += bsum;
                }
                float mnew = fmaxf(mrun, s);
                float rs = expf(mrun - mnew);
                float p = expf(s - mnew);
                denom = denom * rs + p;
                acc = acc * rs + p * bf2f(Vs[j * 128 + h * DH + d]);
                mrun = mnew;
            }
            As[i * LDSP + h * DH + d] = bf16r(acc / denom);   // att_out row i
        }
    }
    __syncthreads();

    // ---- S3: outproj + gate + residual -> val (f32 LDS) ---------------------
    {
        f32x4 a3[4];
#pragma unroll
        for (int i = 0; i < 4; i++)
#pragma unroll
            for (int r = 0; r < 4; r++) a3[i][r] = 0.f;
        gemm_a<4, 4, 4, LDSP>(As + (wave >> 1) * 16 * LDSP, pwo, (wave & 1) * 4, lane, a3);
#pragma unroll
        for (int ntl = 0; ntl < 4; ntl++) {
            int gcol = ((wave & 1) * 4 + ntl) * 16 + cc;
#pragma unroll
            for (int r = 0; r < 4; r++) {
                int lrow = (wave >> 1) * 16 + quad * 4 + r;
                int garow = start + lrow; if (garow > N_ - 1) garow = N_ - 1;
                float v = c_atom[(size_t)(b * N_ + garow) * DA + gcol]
                        + sgf[lrow * 128 + gcol] * a3[ntl][r];
                valf[lrow * 128 + gcol] = v;
            }
        }
    }
    __syncthreads();

    // ---- S3b: LN2 rows -> h (bf16, stride LDSP, in A region) ----------------
    {
        int row = tid >> 3, sub = tid & 7;       // 8 thr/row, 16 cols each
        const float* vr = valf + row * 128 + sub * 16;
        float4 x[4];
        float s = 0.f, sq = 0.f;
#pragma unroll
        for (int i = 0; i < 4; i++) {
            x[i] = *(const float4*)(vr + i * 4);
            s  += x[i].x + x[i].y + x[i].z + x[i].w;
            sq += x[i].x * x[i].x + x[i].y * x[i].y + x[i].z * x[i].z + x[i].w * x[i].w;
        }
        s += __shfl_xor(s, 1); sq += __shfl_xor(sq, 1);
        s += __shfl_xor(s, 2); sq += __shfl_xor(sq, 2);
        s += __shfl_xor(s, 4); sq += __shfl_xor(sq, 4);
        float mean = s * (1.f / 128.f);
        float var = sq * (1.f / 128.f) - mean * mean;
        float inv = rsqrtf(var + 1e-5f);
        short* hr = As + row * LDSP + sub * 16;
        const float* gp = lnfg + sub * 16;
        const float* bp = lnfb + sub * 16;
#pragma unroll
        for (int i = 0; i < 4; i++) {
            hr[i * 4 + 0] = bf16r((x[i].x - mean) * inv * gp[i * 4 + 0] + bp[i * 4 + 0]);
            hr[i * 4 + 1] = bf16r((x[i].y - mean) * inv * gp[i * 4 + 1] + bp[i * 4 + 1]);
            hr[i * 4 + 2] = bf16r((x[i].z - mean) * inv * gp[i * 4 + 2] + bp[i * 4 + 2]);
            hr[i * 4 + 3] = bf16r((x[i].w - mean) * inv * gp[i * 4 + 3] + bp[i * 4 + 3]);
        }
    }
    __syncthreads();

    // ---- S4/S5: ffn1 (chunked over DFF/2) + ffn2 accumulation ---------------
    f32x4 c3a[4];
#pragma unroll
    for (int i = 0; i < 4; i++)
#pragma unroll
        for (int r = 0; r < 4; r++) c3a[i][r] = 0.f;
#pragma unroll
    for (int ch = 0; ch < 2; ch++) {
        // ffn1 chunk: 512 packed cols -> 256 real u cols
        f32x4 u0[8], u1[8];
#pragma unroll
        for (int i = 0; i < 8; i++)
#pragma unroll
            for (int r = 0; r < 4; r++) { u0[i][r] = 0.f; u1[i][r] = 0.f; }
        const short* bp12 = pw12 + ch * 32 * 4 * 512;
        gemm_a<4, 4, 8, LDSP>(As, bp12, wave * 8, lane, u0);
        gemm_a<4, 4, 8, LDSP>(As + 16 * LDSP, bp12, wave * 8, lane, u1);
#pragma unroll
        for (int rt = 0; rt < 2; rt++) {
            f32x4* ac = rt ? u1 : u0;
#pragma unroll
            for (int nt = 0; nt < 8; nt++) {
                int col8 = (wave * 8 + nt) * 8 + (cc >> 1);   // real chunk-local col
#pragma unroll
                for (int r = 0; r < 4; r++) {
                    float v = ac[nt][r];
                    float p = __shfl_xor(v, 1);               // partner (w2)
                    if (!(lane & 1)) {
                        float sil = v / (1.f + expf(-v));
                        us[(rt * 16 + quad * 4 + r) * 264 + col8] = bf16r(sil * p);
                    }
                }
            }
        }
        __syncthreads();
        // ffn2 partial: acc += u_chunk(32x256) @ w3[ch*256:(ch+1)*256, :]
        gemm_a<8, 16, 4, 264>(us + (wave >> 1) * 16 * 264, pw3 + ch * 8 * 512,
                              (wave & 1) * 4, lane, c3a);
        __syncthreads();
    }

    // ---- S6: q2 = bf16(val + ffn2)  (write over val region after full read) -
    {
        float q2v[4][4];
#pragma unroll
        for (int ntl = 0; ntl < 4; ntl++) {
            int gcol = ((wave & 1) * 4 + ntl) * 16 + cc;
#pragma unroll
            for (int r = 0; r < 4; r++) {
                int lrow = (wave >> 1) * 16 + quad * 4 + r;
                q2v[ntl][r] = valf[lrow * 128 + gcol] + c3a[ntl][r];
            }
        }
        __syncthreads();
#pragma unroll
        for (int ntl = 0; ntl < 4; ntl++) {
            int gcol = ((wave & 1) * 4 + ntl) * 16 + cc;
#pragma unroll
            for (int r = 0; r < 4; r++) {
                int lrow = (wave >> 1) * 16 + quad * 4 + r;
                q2s[lrow * 128 + gcol] = bf16r(q2v[ntl][r]);
            }
        }
    }
    __syncthreads();

    // ---- S7: segment mean -> row 0 of mean tile -----------------------------
    if (tid < 128) {
        int col = tid;
        float sum = 0.f;
        for (int i = 0; i < L; i++) sum += bf2f(q2s[i * 128 + col]);
        float inv = (L > 0) ? 1.f / (float)L : 0.f;
        mrs[col] = bf16r(sum * inv);         // row 0 (rows 1..15 garbage, unused)
    }
    __syncthreads();

    // ---- S8: out[token] = mean @ tok_w + tok_b ------------------------------
    {
        f32x4 a8[8];
#pragma unroll
        for (int i = 0; i < 8; i++)
#pragma unroll
            for (int r = 0; r < 4; r++) a8[i][r] = 0.f;
        gemm_a<4, 4, 8, LDSP>(mrs, ptok, wave * 8, lane, a8);
        if (quad == 0) {                      // C row 0 = quad 0, r 0
#pragma unroll
            for (int nt = 0; nt < 8; nt++) {
                int col = (wave * 8 + nt) * 16 + cc;
                out[(size_t)token * DM + col] = a8[nt][0] + tb[col];
            }
        }
    }
}

extern "C" void kernel_launch(void* const* d_in, const int* in_sizes, int n_in,
                              void* d_out, int out_size, void* d_ws, size_t ws_size,
                              hipStream_t stream) {
    const float* c_atom  = (const float*)d_in[0];
    const float* p_lm    = (const float*)d_in[1];
    const int*   p_idx   = (const int*)d_in[2];
    const int*   tok     = (const int*)d_in[3];
    // d_in[4] = n_tokens (512, hardcoded)
    const float* ln_a_g  = (const float*)d_in[5];
    const float* ln_a_b  = (const float*)d_in[6];
    const float* w_q     = (const float*)d_in[7];
    const float* w_k     = (const float*)d_in[8];
    const float* w_v     = (const float*)d_in[9];
    const float* w_g     = (const float*)d_in[10];
    const float* w_o     = (const float*)d_in[11];
    const float* pb_w    = (const float*)d_in[12];
    const float* pb_b    = (const float*)d_in[13];
    const float* ln_f_g  = (const float*)d_in[14];
    const float* ln_f_b  = (const float*)d_in[15];
    const float* sw_w1   = (const float*)d_in[16];
    const float* sw_w2   = (const float*)d_in[17];
    const float* sw_w3   = (const float*)d_in[18];
    const float* tok_w   = (const float*)d_in[19];
    const float* tok_b   = (const float*)d_in[20];
    float* out = (float*)d_out;

    // ---------------- workspace layout ---------------------------------------
    float* ws = (float*)d_ws;
    int*   cnt   = (int*)ws;                       // 1024 i
    int*   tst   = cnt + 1024;                     // 1024 i
    int*   win   = tst + 1024;                     // 131072 i (poison = no winner)
    short* pqkvg = (short*)(win + 131072);         // 65536 bf16
    short* pwo   = pqkvg + 65536;                  // 16384 bf16
    short* pw12  = pwo + 16384;                    // 131072 bf16
    short* pw3   = pw12 + 131072;                  // 65536 bf16
    short* ptok  = pw3 + 65536;                    // 65536 bf16
    short* hln   = ptok + 65536;                   // 524288 bf16 (LN1 rows)

    setup_kernel<<<91, 1024, 0, stream>>>(w_q, w_k, w_v, w_g, w_o, sw_w1, sw_w2,
                                          sw_w3, tok_w, tok, p_idx,
                                          c_atom, ln_a_g, ln_a_b,
                                          pqkvg, pwo, pw12, pw3, ptok, hln,
                                          cnt, tst, win);

    tokfused<<<dim3(B_ * NT), dim3(256), 0, stream>>>(
        hln, c_atom, p_lm, tst, cnt, win,
        pqkvg, pwo, pw12, pw3, ptok,
        pb_w, pb_b, ln_f_g, ln_f_b, tok_b, out);
}

// Round 6
// 199.996 us; speedup vs baseline: 1.6728x; 1.0638x over previous
//
#include <hip/hip_runtime.h>
#include <hip/hip_bf16.h>
#include <math.h>

// Problem constants (fixed by setup_inputs)
#define B_     2
#define N_     2048
#define DA     128
#define H_     4
#define DH     32
#define DFF    512
#define DM     512
#define NT     512
#define NP     16384
#define MAXL   32    // max atoms per token group (validated in prior session)
#define LDSP   136   // padded LDS row stride (shorts) for GEMM-A tiles
#define PVS    40    // padded row stride (shorts) for P / V^T tiles (80B, 16-al)

typedef short bf16x8 __attribute__((ext_vector_type(8)));   // 8 bf16 in 4 VGPRs
typedef float f32x4  __attribute__((ext_vector_type(4)));   // MFMA accumulator

__device__ __forceinline__ short bf16r(float x) {           // RNE fp32->bf16
    union { float f; unsigned u; } v; v.f = x;
    unsigned r = v.u + 0x7FFFu + ((v.u >> 16) & 1u);
    return (short)(r >> 16);
}
__device__ __forceinline__ float bf2f(short h) {
    union { unsigned u; float f; } v;
    v.u = ((unsigned)(unsigned short)h) << 16;
    return v.f;
}

// ------- setup: weight pack (blk 0-41) + hist/scan (blk 42) + pair_win (43-74)
//         + LN1 -> bf16 hln (blk 75-90, 256 rows each)   [verified r0/r2/r5]
__global__ __launch_bounds__(1024) void setup_kernel(
        const float* __restrict__ wq, const float* __restrict__ wk,
        const float* __restrict__ wv, const float* __restrict__ wg,
        const float* __restrict__ wo, const float* __restrict__ w1,
        const float* __restrict__ w2, const float* __restrict__ w3,
        const float* __restrict__ tw, const int* __restrict__ tok,
        const int* __restrict__ pidx,
        const float* __restrict__ c_atom, const float* __restrict__ lng,
        const float* __restrict__ lnb,
        short* __restrict__ pqkvg, short* __restrict__ pwo,
        short* __restrict__ pw12, short* __restrict__ pw3,
        short* __restrict__ ptok, short* __restrict__ hln,
        int* __restrict__ cnt, int* __restrict__ tst,
        int* __restrict__ win) {
    __shared__ int c[1024];
    __shared__ int sb[1024];
    if (blockIdx.x < 42) {
        int gid = blockIdx.x * 1024 + threadIdx.x;   // 0..43007
        int lane = gid & 63;
        int grp = gid >> 6;                          // 0..671
        int quad = lane >> 4, nn = lane & 15;
        const float* src; short* dst; int stride;
        if (grp < 128) {                 // Wqkvg: K=128, N=512 (wq|wk|wv|wg), KT=4
            int g = grp; int kt = g & 3, nt = g >> 2;
            int n = nt * 16 + nn;
            const float* w = (n < 128) ? wq : (n < 256) ? wk : (n < 384) ? wv : wg;
            src = w + (kt * 32 + quad * 8) * 128 + (n & 127);
            dst = pqkvg + (g * 64 + lane) * 8;
            stride = 128;
        } else if (grp < 160) {          // Wo: K=128, N=128, KT=4
            int g = grp - 128; int kt = g & 3, nt = g >> 2;
            src = wo + (kt * 32 + quad * 8) * 128 + nt * 16 + nn;
            dst = pwo + (g * 64 + lane) * 8;
            stride = 128;
        } else if (grp < 416) {          // W12 interleaved: K=128, Npacked=1024, KT=4
            int g = grp - 160; int kt = g & 3, nt = g >> 2;
            int n = nt * 16 + nn;        // even=w1, odd=w2, real col n>>1
            src = ((n & 1) ? w2 : w1) + (kt * 32 + quad * 8) * 512 + (n >> 1);
            dst = pw12 + (g * 64 + lane) * 8;
            stride = 512;
        } else if (grp < 544) {          // W3: K=512, N=128, KT=16
            int g = grp - 416; int kt = g & 15, nt = g >> 4;
            src = w3 + (kt * 32 + quad * 8) * 128 + nt * 16 + nn;
            dst = pw3 + (g * 64 + lane) * 8;
            stride = 128;
        } else {                         // Wtok: K=128, N=512, KT=4
            int g = grp - 544; int kt = g & 3, nt = g >> 2;
            src = tw + (kt * 32 + quad * 8) * 512 + nt * 16 + nn;
            dst = ptok + (g * 64 + lane) * 8;
            stride = 512;
        }
#pragma unroll
        for (int j = 0; j < 8; j++) dst[j] = bf16r(src[j * stride]);
    } else if (blockIdx.x == 42) {
        // histogram + segmented exclusive scan over token counts
        int tid = threadIdx.x;
        c[tid] = 0;
        __syncthreads();
#pragma unroll
        for (int i = 0; i < 4; i++) {
            int idx = tid + i * 1024;           // 0..4095
            int b = idx >> 11;
            atomicAdd(&c[b * NT + tok[idx]], 1);
        }
        __syncthreads();
        int t = tid & (NT - 1);
        int v = c[tid];
        int* cur = c;
        int* alt = sb;
        for (int d = 1; d < NT; d <<= 1) {
            int y = cur[tid];
            if (t >= d) y += cur[tid - d];
            alt[tid] = y;
            __syncthreads();
            int* tmp = cur; cur = alt; alt = tmp;
        }
        tst[tid] = cur[tid] - v;   // exclusive prefix (within batch)
        cnt[tid] = v;
    } else if (blockIdx.x < 75) {
        // pair winner: key by dst&31 (unique within <=32-atom contiguous group);
        // store pp+1 via atomicMax over 0xAA poison (<0) -> no memset needed.
        int p = (blockIdx.x - 43) * 1024 + threadIdx.x;   // 0..32767
        int b = p >> 14, pp = p & (NP - 1);
        int src = pidx[p * 2], dst = pidx[p * 2 + 1];
        if (tok[b * N_ + src] == tok[b * N_ + dst])
            atomicMax(&win[(b * N_ + src) * MAXL + (dst & 31)], pp + 1);
    } else {
        // LN1: 256 rows per block (4 threads/row, 32 cols each) -> bf16 hln
        int t = threadIdx.x;
        int rowg = (blockIdx.x - 75) * 256 + (t >> 2);   // 0..4095
        int sub = t & 3;
        const float* xr = c_atom + rowg * DA + sub * 32;
        float4 v[8];
        float s = 0.f, sq = 0.f;
#pragma unroll
        for (int i = 0; i < 8; i++) {
            v[i] = *(const float4*)(xr + i * 4);
            s  += v[i].x + v[i].y + v[i].z + v[i].w;
            sq += v[i].x * v[i].x + v[i].y * v[i].y + v[i].z * v[i].z + v[i].w * v[i].w;
        }
        s += __shfl_xor(s, 1); sq += __shfl_xor(sq, 1);
        s += __shfl_xor(s, 2); sq += __shfl_xor(sq, 2);
        float mean = s * (1.f / 128.f);
        float var = sq * (1.f / 128.f) - mean * mean;
        float inv = rsqrtf(var + 1e-5f);
        const float* gp = lng + sub * 32;
        const float* bp = lnb + sub * 32;
        short* dst = hln + rowg * DA + sub * 32;
#pragma unroll
        for (int i = 0; i < 8; i++) {
            dst[i * 4 + 0] = bf16r((v[i].x - mean) * inv * gp[i * 4 + 0] + bp[i * 4 + 0]);
            dst[i * 4 + 1] = bf16r((v[i].y - mean) * inv * gp[i * 4 + 1] + bp[i * 4 + 1]);
            dst[i * 4 + 2] = bf16r((v[i].z - mean) * inv * gp[i * 4 + 2] + bp[i * 4 + 2]);
            dst[i * 4 + 3] = bf16r((v[i].w - mean) * inv * gp[i * 4 + 3] + bp[i * 4 + 3]);
        }
    }
}

// -------- generic MFMA GEMM core: A from LDS (stride STR), B packed ----------
// A-frag: row=lane&15 (+row-tile offset in Abase), k=(lane>>4)*8 + kt*32.
// B-frag: (nt*KTB + kt)*512 + lane*8.  C: row=quad*4+r, col=lane&15. [verified]
template<int KT, int KTB, int NTT, int STR>
__device__ __forceinline__ void gemm_a(const short* __restrict__ Abase,
                                       const short* __restrict__ Bp,
                                       int nt0, int lane, f32x4* acc) {
    const short* arow = Abase + (lane & 15) * STR + (lane >> 4) * 8;
    const short* bbase = Bp + lane * 8;
#pragma unroll
    for (int kt = 0; kt < KT; kt++) {
        bf16x8 a = *(const bf16x8*)(arow + kt * 32);
#pragma unroll
        for (int nt = 0; nt < NTT; nt++) {
            bf16x8 b = *(const bf16x8*)(bbase + ((nt0 + nt) * KTB + kt) * 512);
            acc[nt] = __builtin_amdgcn_mfma_f32_16x16x32_bf16(a, b, acc[nt], 0, 0, 0);
        }
    }
}

// =============================================================================
// tokfused: one block per token group (<=32 contiguous atoms). Entire post-LN1
// pipeline in LDS/registers. Attention via MFMA (wave = head):
//   S = Q K^T (4 mfma) -> reg softmax (16-lane shfl) -> P(bf16) -> out^T=V^T P^T
// 1024 blocks x 256 thr.
// =============================================================================
// LDS arena (54272 B):
//   As  [    0.. 8704) 32x136 bf16: staged A / att_out / h(LN2)
//   Qs  [ 8704..18944) 32x136 bf16 Q; overlaid by Ps[h][32][PVS] after QK^T
//   Ks  [18944..27648) 32x136 bf16 K
//   VT  [27648..37888) [h][d=32][PVS] bf16 V-transposed
//   sgf [37888..54272) 32x128 f32 sigmoid(G)
//   overlays: valf(f32 32x128)->8704..25088 ; us(32x264 bf16)->27648..44544 ;
//             q2s(32x128 bf16)->0..8192 ; mrs(16x136 bf16)->25088..29440
__global__ __launch_bounds__(256, 2) void tokfused(
        const short* __restrict__ hln, const float* __restrict__ c_atom,
        const float* __restrict__ plm,
        const int* __restrict__ tst, const int* __restrict__ cnt,
        const int* __restrict__ win,
        const short* __restrict__ pqkvg, const short* __restrict__ pwo,
        const short* __restrict__ pw12, const short* __restrict__ pw3,
        const short* __restrict__ ptok,
        const float* __restrict__ pbw, const float* __restrict__ pbb,
        const float* __restrict__ lnfg, const float* __restrict__ lnfb,
        const float* __restrict__ tb, float* __restrict__ out) {
    __shared__ __align__(16) char arena[54272];
    short* As  = (short*)(arena + 0);
    short* Qs  = (short*)(arena + 8704);
    short* Ps  = (short*)(arena + 8704);     // P overlays Q after QK^T
    short* Ks  = (short*)(arena + 18944);
    short* VT  = (short*)(arena + 27648);    // [h][d][PVS]
    float* sgf = (float*)(arena + 37888);
    float* valf = (float*)(arena + 8704);
    short* us   = (short*)(arena + 27648);   // 32x264
    short* q2s  = (short*)(arena + 0);
    short* mrs  = (short*)(arena + 25088);   // 16x136

    int token = blockIdx.x;                  // b*NT + t
    int b = token >> 9;
    int tid = threadIdx.x;
    int lane = tid & 63, wave = tid >> 6;
    int quad = lane >> 4, cc = lane & 15;
    int start = tst[token];
    int L = cnt[token]; if (L > MAXL) L = MAXL;

    // ---- S0: stage hln rows (zeros beyond L) --------------------------------
    {
        int row = tid >> 3, sub = tid & 7;       // 32 rows x 8 chunks of 16
        int4 v0 = {0,0,0,0}, v1 = {0,0,0,0};
        if (row < L) {
            const int4* src = (const int4*)(hln + (size_t)(b * N_ + start + row) * DA + sub * 16);
            v0 = src[0]; v1 = src[1];
        }
        int4* dst = (int4*)(As + row * LDSP + sub * 16);
        dst[0] = v0; dst[1] = v1;
    }
    __syncthreads();

    // ---- S1: QKVG = A(32x128) @ pqkvg(128x512) ------------------------------
    // wave w covers cols w*128..w*128+127:  w0->Q, w1->K, w2->V^T, w3->sigmoid(G)
    {
        f32x4 a0[8], a1[8];
#pragma unroll
        for (int i = 0; i < 8; i++)
#pragma unroll
            for (int r = 0; r < 4; r++) { a0[i][r] = 0.f; a1[i][r] = 0.f; }
        gemm_a<4, 4, 8, LDSP>(As, pqkvg, wave * 8, lane, a0);
        gemm_a<4, 4, 8, LDSP>(As + 16 * LDSP, pqkvg, wave * 8, lane, a1);
#pragma unroll
        for (int rt = 0; rt < 2; rt++) {
            f32x4* ac = rt ? a1 : a0;
#pragma unroll
            for (int nt = 0; nt < 8; nt++) {
                int lc = nt * 16 + cc;           // col within wave's 128-segment
#pragma unroll
                for (int r = 0; r < 4; r++) {
                    int lrow = rt * 16 + quad * 4 + r;
                    float v = ac[nt][r];
                    if (wave == 3)      sgf[lrow * 128 + lc] = 1.f / (1.f + expf(-v));
                    else if (wave == 0) Qs[lrow * LDSP + lc] = bf16r(v);
                    else if (wave == 1) Ks[lrow * LDSP + lc] = bf16r(v);
                    else VT[(lc >> 5) * 32 * PVS + (lc & 31) * PVS + lrow] = bf16r(v);
                }
            }
        }
    }
    __syncthreads();

    // ---- S2: MFMA attention (wave = head) -----------------------------------
    {
        int h = wave;
        const float scale = 0.17677669529663687f;   // 1/sqrt(32)
        int rb = lane & 15;
        // QK^T: S(i,j) tiles (it,jt), K=32 single mfma each
        bf16x8 qa0 = *(const bf16x8*)(Qs + rb * LDSP + h * 32 + quad * 8);
        bf16x8 qa1 = *(const bf16x8*)(Qs + (16 + rb) * LDSP + h * 32 + quad * 8);
        bf16x8 kb0 = *(const bf16x8*)(Ks + rb * LDSP + h * 32 + quad * 8);
        bf16x8 kb1 = *(const bf16x8*)(Ks + (16 + rb) * LDSP + h * 32 + quad * 8);
        f32x4 z = {0.f, 0.f, 0.f, 0.f};
        f32x4 sc[2][2];
        sc[0][0] = __builtin_amdgcn_mfma_f32_16x16x32_bf16(qa0, kb0, z, 0, 0, 0);
        sc[0][1] = __builtin_amdgcn_mfma_f32_16x16x32_bf16(qa0, kb1, z, 0, 0, 0);
        sc[1][0] = __builtin_amdgcn_mfma_f32_16x16x32_bf16(qa1, kb0, z, 0, 0, 0);
        sc[1][1] = __builtin_amdgcn_mfma_f32_16x16x32_bf16(qa1, kb1, z, 0, 0, 0);
        __syncthreads();                  // all Q/K reads done before P overlay
        short* Ph = Ps + h * 32 * PVS;
        int j0 = cc, j1 = 16 + cc;
#pragma unroll
        for (int it = 0; it < 2; it++) {
#pragma unroll
            for (int r = 0; r < 4; r++) {
                int i = it * 16 + quad * 4 + r;
                int at = start + i; if (at > N_ - 1) at = N_ - 1;   // clamp (rows >= L unused)
                const int* wrow = win + (size_t)(b * N_ + at) * MAXL;
                float s0 = sc[it][0][r] * scale;
                float s1 = sc[it][1][r] * scale;
                int pw0 = (j0 < L) ? wrow[(start + j0) & 31] : 0;
                int pw1 = (j1 < L) ? wrow[(start + j1) & 31] : 0;
                if (pw0 > 0) {            // rare winning-pair bias
                    const float* pl = plm + (size_t)(b * NP + pw0 - 1) * 16;
                    float bs = pbb[h];
#pragma unroll
                    for (int f = 0; f < 16; f++) bs += pl[f] * pbw[f * H_ + h];
                    s0 += bs;
                }
                if (pw1 > 0) {
                    const float* pl = plm + (size_t)(b * NP + pw1 - 1) * 16;
                    float bs = pbb[h];
#pragma unroll
                    for (int f = 0; f < 16; f++) bs += pl[f] * pbw[f * H_ + h];
                    s1 += bs;
                }
                if (j0 >= L) s0 = -1e30f;
                if (j1 >= L) s1 = -1e30f;
                float m = fmaxf(s0, s1);
                m = fmaxf(m, __shfl_xor(m, 1));
                m = fmaxf(m, __shfl_xor(m, 2));
                m = fmaxf(m, __shfl_xor(m, 4));
                m = fmaxf(m, __shfl_xor(m, 8));
                float e0 = expf(s0 - m), e1 = expf(s1 - m);
                float sm = e0 + e1;
                sm += __shfl_xor(sm, 1);
                sm += __shfl_xor(sm, 2);
                sm += __shfl_xor(sm, 4);
                sm += __shfl_xor(sm, 8);
                float inv = 1.f / sm;
                Ph[i * PVS + j0] = bf16r(e0 * inv);
                Ph[i * PVS + j1] = bf16r(e1 * inv);
            }
        }
        __syncthreads();
        // PV: out^T[d][i] = sum_j V^T[d][j] P^T[j][i];  A=V^T rows d, B=P rows i
        const short* Vh = VT + h * 32 * PVS;
        bf16x8 va0 = *(const bf16x8*)(Vh + rb * PVS + quad * 8);
        bf16x8 va1 = *(const bf16x8*)(Vh + (16 + rb) * PVS + quad * 8);
        bf16x8 pb0 = *(const bf16x8*)(Ph + rb * PVS + quad * 8);
        bf16x8 pb1 = *(const bf16x8*)(Ph + (16 + rb) * PVS + quad * 8);
        f32x4 ot[2][2];                   // [d-tile][i-tile]
        ot[0][0] = __builtin_amdgcn_mfma_f32_16x16x32_bf16(va0, pb0, z, 0, 0, 0);
        ot[0][1] = __builtin_amdgcn_mfma_f32_16x16x32_bf16(va0, pb1, z, 0, 0, 0);
        ot[1][0] = __builtin_amdgcn_mfma_f32_16x16x32_bf16(va1, pb0, z, 0, 0, 0);
        ot[1][1] = __builtin_amdgcn_mfma_f32_16x16x32_bf16(va1, pb1, z, 0, 0, 0);
#pragma unroll
        for (int dt = 0; dt < 2; dt++)
#pragma unroll
            for (int itile = 0; itile < 2; itile++)
#pragma unroll
                for (int r = 0; r < 4; r++)
                    As[(itile * 16 + cc) * LDSP + h * 32 + dt * 16 + quad * 4 + r] =
                        bf16r(ot[dt][itile][r]);
    }
    __syncthreads();

    // ---- S3: outproj + gate + residual -> val (f32 LDS) ---------------------
    {
        f32x4 a3[4];
#pragma unroll
        for (int i = 0; i < 4; i++)
#pragma unroll
            for (int r = 0; r < 4; r++) a3[i][r] = 0.f;
        gemm_a<4, 4, 4, LDSP>(As + (wave >> 1) * 16 * LDSP, pwo, (wave & 1) * 4, lane, a3);
#pragma unroll
        for (int ntl = 0; ntl < 4; ntl++) {
            int gcol = ((wave & 1) * 4 + ntl) * 16 + cc;
#pragma unroll
            for (int r = 0; r < 4; r++) {
                int lrow = (wave >> 1) * 16 + quad * 4 + r;
                int garow = start + lrow; if (garow > N_ - 1) garow = N_ - 1;
                float v = c_atom[(size_t)(b * N_ + garow) * DA + gcol]
                        + sgf[lrow * 128 + gcol] * a3[ntl][r];
                valf[lrow * 128 + gcol] = v;
            }
        }
    }
    __syncthreads();

    // ---- S3b: LN2 rows -> h (bf16, stride LDSP, in A region) ----------------
    {
        int row = tid >> 3, sub = tid & 7;       // 8 thr/row, 16 cols each
        const float* vr = valf + row * 128 + sub * 16;
        float4 x[4];
        float s = 0.f, sq = 0.f;
#pragma unroll
        for (int i = 0; i < 4; i++) {
            x[i] = *(const float4*)(vr + i * 4);
            s  += x[i].x + x[i].y + x[i].z + x[i].w;
            sq += x[i].x * x[i].x + x[i].y * x[i].y + x[i].z * x[i].z + x[i].w * x[i].w;
        }
        s += __shfl_xor(s, 1); sq += __shfl_xor(sq, 1);
        s += __shfl_xor(s, 2); sq += __shfl_xor(sq, 2);
        s += __shfl_xor(s, 4); sq += __shfl_xor(sq, 4);
        float mean = s * (1.f / 128.f);
        float var = sq * (1.f / 128.f) - mean * mean;
        float inv = rsqrtf(var + 1e-5f);
        short* hr = As + row * LDSP + sub * 16;
        const float* gp = lnfg + sub * 16;
        const float* bp = lnfb + sub * 16;
#pragma unroll
        for (int i = 0; i < 4; i++) {
            hr[i * 4 + 0] = bf16r((x[i].x - mean) * inv * gp[i * 4 + 0] + bp[i * 4 + 0]);
            hr[i * 4 + 1] = bf16r((x[i].y - mean) * inv * gp[i * 4 + 1] + bp[i * 4 + 1]);
            hr[i * 4 + 2] = bf16r((x[i].z - mean) * inv * gp[i * 4 + 2] + bp[i * 4 + 2]);
            hr[i * 4 + 3] = bf16r((x[i].w - mean) * inv * gp[i * 4 + 3] + bp[i * 4 + 3]);
        }
    }
    __syncthreads();

    // ---- S4/S5: ffn1 (chunked over DFF/2) + ffn2 accumulation ---------------
    f32x4 c3a[4];
#pragma unroll
    for (int i = 0; i < 4; i++)
#pragma unroll
        for (int r = 0; r < 4; r++) c3a[i][r] = 0.f;
#pragma unroll
    for (int ch = 0; ch < 2; ch++) {
        // ffn1 chunk: 512 packed cols -> 256 real u cols
        f32x4 u0[8], u1[8];
#pragma unroll
        for (int i = 0; i < 8; i++)
#pragma unroll
            for (int r = 0; r < 4; r++) { u0[i][r] = 0.f; u1[i][r] = 0.f; }
        const short* bp12 = pw12 + ch * 32 * 4 * 512;
        gemm_a<4, 4, 8, LDSP>(As, bp12, wave * 8, lane, u0);
        gemm_a<4, 4, 8, LDSP>(As + 16 * LDSP, bp12, wave * 8, lane, u1);
#pragma unroll
        for (int rt = 0; rt < 2; rt++) {
            f32x4* ac = rt ? u1 : u0;
#pragma unroll
            for (int nt = 0; nt < 8; nt++) {
                int col8 = (wave * 8 + nt) * 8 + (cc >> 1);   // real chunk-local col
#pragma unroll
                for (int r = 0; r < 4; r++) {
                    float v = ac[nt][r];
                    float p = __shfl_xor(v, 1);               // partner (w2)
                    if (!(lane & 1)) {
                        float sil = v / (1.f + expf(-v));
                        us[(rt * 16 + quad * 4 + r) * 264 + col8] = bf16r(sil * p);
                    }
                }
            }
        }
        __syncthreads();
        // ffn2 partial: acc += u_chunk(32x256) @ w3[ch*256:(ch+1)*256, :]
        gemm_a<8, 16, 4, 264>(us + (wave >> 1) * 16 * 264, pw3 + ch * 8 * 512,
                              (wave & 1) * 4, lane, c3a);
        __syncthreads();
    }

    // ---- S6: q2 = bf16(val + ffn2)  (q2s region distinct from valf) ---------
    {
#pragma unroll
        for (int ntl = 0; ntl < 4; ntl++) {
            int gcol = ((wave & 1) * 4 + ntl) * 16 + cc;
#pragma unroll
            for (int r = 0; r < 4; r++) {
                int lrow = (wave >> 1) * 16 + quad * 4 + r;
                q2s[lrow * 128 + gcol] = bf16r(valf[lrow * 128 + gcol] + c3a[ntl][r]);
            }
        }
    }
    __syncthreads();

    // ---- S7: segment mean -> row 0 of mean tile -----------------------------
    if (tid < 128) {
        int col = tid;
        float sum = 0.f;
        for (int i = 0; i < L; i++) sum += bf2f(q2s[i * 128 + col]);
        float inv = (L > 0) ? 1.f / (float)L : 0.f;
        mrs[col] = bf16r(sum * inv);         // row 0 (rows 1..15 garbage: C-row isolated)
    }
    __syncthreads();

    // ---- S8: out[token] = mean @ tok_w + tok_b ------------------------------
    {
        f32x4 a8[8];
#pragma unroll
        for (int i = 0; i < 8; i++)
#pragma unroll
            for (int r = 0; r < 4; r++) a8[i][r] = 0.f;
        gemm_a<4, 4, 8, LDSP>(mrs, ptok, wave * 8, lane, a8);
        if (quad == 0) {                      // C row 0 = quad 0, r 0
#pragma unroll
            for (int nt = 0; nt < 8; nt++) {
                int col = (wave * 8 + nt) * 16 + cc;
                out[(size_t)token * DM + col] = a8[nt][0] + tb[col];
            }
        }
    }
}

extern "C" void kernel_launch(void* const* d_in, const int* in_sizes, int n_in,
                              void* d_out, int out_size, void* d_ws, size_t ws_size,
                              hipStream_t stream) {
    const float* c_atom  = (const float*)d_in[0];
    const float* p_lm    = (const float*)d_in[1];
    const int*   p_idx   = (const int*)d_in[2];
    const int*   tok     = (const int*)d_in[3];
    // d_in[4] = n_tokens (512, hardcoded)
    const float* ln_a_g  = (const float*)d_in[5];
    const float* ln_a_b  = (const float*)d_in[6];
    const float* w_q     = (const float*)d_in[7];
    const float* w_k     = (const float*)d_in[8];
    const float* w_v     = (const float*)d_in[9];
    const float* w_g     = (const float*)d_in[10];
    const float* w_o     = (const float*)d_in[11];
    const float* pb_w    = (const float*)d_in[12];
    const float* pb_b    = (const float*)d_in[13];
    const float* ln_f_g  = (const float*)d_in[14];
    const float* ln_f_b  = (const float*)d_in[15];
    const float* sw_w1   = (const float*)d_in[16];
    const float* sw_w2   = (const float*)d_in[17];
    const float* sw_w3   = (const float*)d_in[18];
    const float* tok_w   = (const float*)d_in[19];
    const float* tok_b   = (const float*)d_in[20];
    float* out = (float*)d_out;

    // ---------------- workspace layout ---------------------------------------
    float* ws = (float*)d_ws;
    int*   cnt   = (int*)ws;                       // 1024 i
    int*   tst   = cnt + 1024;                     // 1024 i
    int*   win   = tst + 1024;                     // 131072 i (poison = no winner)
    short* pqkvg = (short*)(win + 131072);         // 65536 bf16
    short* pwo   = pqkvg + 65536;                  // 16384 bf16
    short* pw12  = pwo + 16384;                    // 131072 bf16
    short* pw3   = pw12 + 131072;                  // 65536 bf16
    short* ptok  = pw3 + 65536;                    // 65536 bf16
    short* hln   = ptok + 65536;                   // 524288 bf16 (LN1 rows)

    setup_kernel<<<91, 1024, 0, stream>>>(w_q, w_k, w_v, w_g, w_o, sw_w1, sw_w2,
                                          sw_w3, tok_w, tok, p_idx,
                                          c_atom, ln_a_g, ln_a_b,
                                          pqkvg, pwo, pw12, pw3, ptok, hln,
                                          cnt, tst, win);

    tokfused<<<dim3(B_ * NT), dim3(256), 0, stream>>>(
        hln, c_atom, p_lm, tst, cnt, win,
        pqkvg, pwo, pw12, pw3, ptok,
        pb_w, pb_b, ln_f_g, ln_f_b, tok_b, out);
}

// Round 7
// 166.013 us; speedup vs baseline: 2.0152x; 1.2047x over previous
//
#include <hip/hip_runtime.h>
#include <hip/hip_bf16.h>
#include <math.h>

// Problem constants (fixed by setup_inputs)
#define B_     2
#define N_     2048
#define DA     128
#define H_     4
#define DH     32
#define DFF    512
#define DM     512
#define NT     512
#define NP     16384
#define MAXL   32    // max atoms per token group (validated in prior session)
#define LDSP   136   // padded LDS row stride (shorts) for GEMM-A tiles
#define PVS    40    // padded row stride (shorts) for P / V^T tiles (80B, 16-al)

typedef short bf16x8 __attribute__((ext_vector_type(8)));   // 8 bf16 in 4 VGPRs
typedef float f32x4  __attribute__((ext_vector_type(4)));   // MFMA accumulator

__device__ __forceinline__ short bf16r(float x) {           // RNE fp32->bf16
    union { float f; unsigned u; } v; v.f = x;
    unsigned r = v.u + 0x7FFFu + ((v.u >> 16) & 1u);
    return (short)(r >> 16);
}
__device__ __forceinline__ float bf2f(short h) {
    union { unsigned u; float f; } v;
    v.u = ((unsigned)(unsigned short)h) << 16;
    return v.f;
}

// ------- setup: weight pack (blk 0-41) + hist/scan (blk 42) + pair_win (43-74)
//         + LN1 -> bf16 hln (blk 75-90, 256 rows each)   [verified r0/r2/r5]
__global__ __launch_bounds__(1024) void setup_kernel(
        const float* __restrict__ wq, const float* __restrict__ wk,
        const float* __restrict__ wv, const float* __restrict__ wg,
        const float* __restrict__ wo, const float* __restrict__ w1,
        const float* __restrict__ w2, const float* __restrict__ w3,
        const float* __restrict__ tw, const int* __restrict__ tok,
        const int* __restrict__ pidx,
        const float* __restrict__ c_atom, const float* __restrict__ lng,
        const float* __restrict__ lnb,
        short* __restrict__ pqkvg, short* __restrict__ pwo,
        short* __restrict__ pw12, short* __restrict__ pw3,
        short* __restrict__ ptok, short* __restrict__ hln,
        int* __restrict__ cnt, int* __restrict__ tst,
        int* __restrict__ win) {
    __shared__ int c[1024];
    __shared__ int sb[1024];
    if (blockIdx.x < 42) {
        int gid = blockIdx.x * 1024 + threadIdx.x;   // 0..43007
        int lane = gid & 63;
        int grp = gid >> 6;                          // 0..671
        int quad = lane >> 4, nn = lane & 15;
        const float* src; short* dst; int stride;
        if (grp < 128) {                 // Wqkvg: K=128, N=512 (wq|wk|wv|wg), KT=4
            int g = grp; int kt = g & 3, nt = g >> 2;
            int n = nt * 16 + nn;
            const float* w = (n < 128) ? wq : (n < 256) ? wk : (n < 384) ? wv : wg;
            src = w + (kt * 32 + quad * 8) * 128 + (n & 127);
            dst = pqkvg + (g * 64 + lane) * 8;
            stride = 128;
        } else if (grp < 160) {          // Wo: K=128, N=128, KT=4
            int g = grp - 128; int kt = g & 3, nt = g >> 2;
            src = wo + (kt * 32 + quad * 8) * 128 + nt * 16 + nn;
            dst = pwo + (g * 64 + lane) * 8;
            stride = 128;
        } else if (grp < 416) {          // W12 interleaved: K=128, Npacked=1024, KT=4
            int g = grp - 160; int kt = g & 3, nt = g >> 2;
            int n = nt * 16 + nn;        // even=w1, odd=w2, real col n>>1
            src = ((n & 1) ? w2 : w1) + (kt * 32 + quad * 8) * 512 + (n >> 1);
            dst = pw12 + (g * 64 + lane) * 8;
            stride = 512;
        } else if (grp < 544) {          // W3: K=512, N=128, KT=16
            int g = grp - 416; int kt = g & 15, nt = g >> 4;
            src = w3 + (kt * 32 + quad * 8) * 128 + nt * 16 + nn;
            dst = pw3 + (g * 64 + lane) * 8;
            stride = 128;
        } else {                         // Wtok: K=128, N=512, KT=4
            int g = grp - 544; int kt = g & 3, nt = g >> 2;
            src = tw + (kt * 32 + quad * 8) * 512 + nt * 16 + nn;
            dst = ptok + (g * 64 + lane) * 8;
            stride = 512;
        }
#pragma unroll
        for (int j = 0; j < 8; j++) dst[j] = bf16r(src[j * stride]);
    } else if (blockIdx.x == 42) {
        // histogram + segmented exclusive scan over token counts
        int tid = threadIdx.x;
        c[tid] = 0;
        __syncthreads();
#pragma unroll
        for (int i = 0; i < 4; i++) {
            int idx = tid + i * 1024;           // 0..4095
            int b = idx >> 11;
            atomicAdd(&c[b * NT + tok[idx]], 1);
        }
        __syncthreads();
        int t = tid & (NT - 1);
        int v = c[tid];
        int* cur = c;
        int* alt = sb;
        for (int d = 1; d < NT; d <<= 1) {
            int y = cur[tid];
            if (t >= d) y += cur[tid - d];
            alt[tid] = y;
            __syncthreads();
            int* tmp = cur; cur = alt; alt = tmp;
        }
        tst[tid] = cur[tid] - v;   // exclusive prefix (within batch)
        cnt[tid] = v;
    } else if (blockIdx.x < 75) {
        // pair winner: key by dst&31 (unique within <=32-atom contiguous group);
        // store pp+1 via atomicMax over 0xAA poison (<0) -> no memset needed.
        int p = (blockIdx.x - 43) * 1024 + threadIdx.x;   // 0..32767
        int b = p >> 14, pp = p & (NP - 1);
        int src = pidx[p * 2], dst = pidx[p * 2 + 1];
        if (tok[b * N_ + src] == tok[b * N_ + dst])
            atomicMax(&win[(b * N_ + src) * MAXL + (dst & 31)], pp + 1);
    } else {
        // LN1: 256 rows per block (4 threads/row, 32 cols each) -> bf16 hln
        int t = threadIdx.x;
        int rowg = (blockIdx.x - 75) * 256 + (t >> 2);   // 0..4095
        int sub = t & 3;
        const float* xr = c_atom + rowg * DA + sub * 32;
        float4 v[8];
        float s = 0.f, sq = 0.f;
#pragma unroll
        for (int i = 0; i < 8; i++) {
            v[i] = *(const float4*)(xr + i * 4);
            s  += v[i].x + v[i].y + v[i].z + v[i].w;
            sq += v[i].x * v[i].x + v[i].y * v[i].y + v[i].z * v[i].z + v[i].w * v[i].w;
        }
        s += __shfl_xor(s, 1); sq += __shfl_xor(sq, 1);
        s += __shfl_xor(s, 2); sq += __shfl_xor(sq, 2);
        float mean = s * (1.f / 128.f);
        float var = sq * (1.f / 128.f) - mean * mean;
        float inv = rsqrtf(var + 1e-5f);
        const float* gp = lng + sub * 32;
        const float* bp = lnb + sub * 32;
        short* dst = hln + rowg * DA + sub * 32;
#pragma unroll
        for (int i = 0; i < 8; i++) {
            dst[i * 4 + 0] = bf16r((v[i].x - mean) * inv * gp[i * 4 + 0] + bp[i * 4 + 0]);
            dst[i * 4 + 1] = bf16r((v[i].y - mean) * inv * gp[i * 4 + 1] + bp[i * 4 + 1]);
            dst[i * 4 + 2] = bf16r((v[i].z - mean) * inv * gp[i * 4 + 2] + bp[i * 4 + 2]);
            dst[i * 4 + 3] = bf16r((v[i].w - mean) * inv * gp[i * 4 + 3] + bp[i * 4 + 3]);
        }
    }
}

// ------- biasfill: winner pair -> 4 per-head bias floats (after setup) -------
__global__ __launch_bounds__(1024) void biasfill(
        const int* __restrict__ pidx, const int* __restrict__ tok,
        const int* __restrict__ win, const float* __restrict__ plm,
        const float* __restrict__ pbw, const float* __restrict__ pbb,
        float* __restrict__ biasT) {
    int p = blockIdx.x * 1024 + threadIdx.x;   // 0..32767 (= b*NP+pp)
    int b = p >> 14, pp = p & (NP - 1);
    int src = pidx[p * 2], dst = pidx[p * 2 + 1];
    if (tok[b * N_ + src] != tok[b * N_ + dst]) return;
    int key = (b * N_ + src) * MAXL + (dst & 31);
    if (win[key] != pp + 1) return;            // only the winning pair writes
    const float* pl = plm + (size_t)p * 16;
#pragma unroll
    for (int h = 0; h < H_; h++) {
        float bs = pbb[h];
#pragma unroll
        for (int f = 0; f < 16; f++) bs += pl[f] * pbw[f * H_ + h];
        biasT[(size_t)key * 4 + h] = bs;
    }
}

// -------- generic MFMA GEMM core: A from LDS (stride STR), B packed ----------
template<int KT, int KTB, int NTT, int STR>
__device__ __forceinline__ void gemm_a(const short* __restrict__ Abase,
                                       const short* __restrict__ Bp,
                                       int nt0, int lane, f32x4* acc) {
    const short* arow = Abase + (lane & 15) * STR + (lane >> 4) * 8;
    const short* bbase = Bp + lane * 8;
#pragma unroll
    for (int kt = 0; kt < KT; kt++) {
        bf16x8 a = *(const bf16x8*)(arow + kt * 32);
#pragma unroll
        for (int nt = 0; nt < NTT; nt++) {
            bf16x8 b = *(const bf16x8*)(bbase + ((nt0 + nt) * KTB + kt) * 512);
            acc[nt] = __builtin_amdgcn_mfma_f32_16x16x32_bf16(a, b, acc[nt], 0, 0, 0);
        }
    }
}

// =============================================================================
// tokfused: one block per token group. Fast path for L<=16 (typical L~4):
// all 32-row tiles collapse to 16-row tiles; fast-exp; precomputed pair bias.
// =============================================================================
__global__ __launch_bounds__(256, 2) void tokfused(
        const short* __restrict__ hln, const float* __restrict__ c_atom,
        const float* __restrict__ biasT,
        const int* __restrict__ tst, const int* __restrict__ cnt,
        const int* __restrict__ win,
        const short* __restrict__ pqkvg, const short* __restrict__ pwo,
        const short* __restrict__ pw12, const short* __restrict__ pw3,
        const short* __restrict__ ptok,
        const float* __restrict__ lnfg, const float* __restrict__ lnfb,
        const float* __restrict__ tb, float* __restrict__ out) {
    __shared__ __align__(16) char arena[54272];
    short* As  = (short*)(arena + 0);
    short* Qs  = (short*)(arena + 8704);
    short* Ps  = (short*)(arena + 8704);     // P overlays Q after QK^T
    short* Ks  = (short*)(arena + 18944);
    short* VT  = (short*)(arena + 27648);    // [h][d][PVS]
    float* sgf = (float*)(arena + 37888);
    float* valf = (float*)(arena + 8704);
    short* us   = (short*)(arena + 27648);   // 32x264
    short* q2s  = (short*)(arena + 0);
    short* mrs  = (short*)(arena + 25088);   // 16x136

    int token = blockIdx.x;                  // b*NT + t
    int b = token >> 9;
    int tid = threadIdx.x;
    int lane = tid & 63, wave = tid >> 6;
    int quad = lane >> 4, cc = lane & 15;
    int start = tst[token];
    int L = cnt[token]; if (L > MAXL) L = MAXL;
    const bool fast = (L <= 16);             // block-uniform

    // ---- S0: stage hln rows (zeros beyond L); zero VT region if fast --------
    {
        int row = tid >> 3, sub = tid & 7;       // 32 rows x 8 chunks of 16
        int4 v0 = {0,0,0,0}, v1 = {0,0,0,0};
        if (row < L) {
            const int4* src = (const int4*)(hln + (size_t)(b * N_ + start + row) * DA + sub * 16);
            v0 = src[0]; v1 = src[1];
        }
        int4* dst = (int4*)(As + row * LDSP + sub * 16);
        dst[0] = v0; dst[1] = v1;
        if (fast) {                          // zero VT (PV contracts over all 32 j)
            int4* vz = (int4*)(arena + 27648);
            int4 zz = {0,0,0,0};
#pragma unroll
            for (int k = 0; k < 3; k++) {
                int idx = tid + k * 256;
                if (idx < 640) vz[idx] = zz;
            }
        }
    }
    __syncthreads();

    // ---- S1: QKVG = A @ pqkvg;  w0->Q, w1->K, w2->V^T, w3->sigmoid(G) -------
    {
        f32x4 a0[8], a1[8];
#pragma unroll
        for (int i = 0; i < 8; i++)
#pragma unroll
            for (int r = 0; r < 4; r++) { a0[i][r] = 0.f; a1[i][r] = 0.f; }
        gemm_a<4, 4, 8, LDSP>(As, pqkvg, wave * 8, lane, a0);
        if (!fast) gemm_a<4, 4, 8, LDSP>(As + 16 * LDSP, pqkvg, wave * 8, lane, a1);
#pragma unroll
        for (int rt = 0; rt < 2; rt++) {
            if (rt == 1 && fast) break;
            f32x4* ac = rt ? a1 : a0;
#pragma unroll
            for (int nt = 0; nt < 8; nt++) {
                int lc = nt * 16 + cc;           // col within wave's 128-segment
#pragma unroll
                for (int r = 0; r < 4; r++) {
                    int lrow = rt * 16 + quad * 4 + r;
                    float v = ac[nt][r];
                    if (wave == 3)      sgf[lrow * 128 + lc] = 1.f / (1.f + __expf(-v));
                    else if (wave == 0) Qs[lrow * LDSP + lc] = bf16r(v);
                    else if (wave == 1) Ks[lrow * LDSP + lc] = bf16r(v);
                    else VT[(lc >> 5) * 32 * PVS + (lc & 31) * PVS + lrow] = bf16r(v);
                }
            }
        }
    }
    __syncthreads();

    // ---- S2: MFMA attention (wave = head) -----------------------------------
    {
        int h = wave;
        const float scale = 0.17677669529663687f;   // 1/sqrt(32)
        int rb = lane & 15;
        f32x4 z = {0.f, 0.f, 0.f, 0.f};
        bf16x8 qa0 = *(const bf16x8*)(Qs + rb * LDSP + h * 32 + quad * 8);
        bf16x8 kb0 = *(const bf16x8*)(Ks + rb * LDSP + h * 32 + quad * 8);
        f32x4 sc00 = __builtin_amdgcn_mfma_f32_16x16x32_bf16(qa0, kb0, z, 0, 0, 0);
        f32x4 sc01 = z, sc10 = z, sc11 = z;
        if (!fast) {
            bf16x8 qa1 = *(const bf16x8*)(Qs + (16 + rb) * LDSP + h * 32 + quad * 8);
            bf16x8 kb1 = *(const bf16x8*)(Ks + (16 + rb) * LDSP + h * 32 + quad * 8);
            sc01 = __builtin_amdgcn_mfma_f32_16x16x32_bf16(qa0, kb1, z, 0, 0, 0);
            sc10 = __builtin_amdgcn_mfma_f32_16x16x32_bf16(qa1, kb0, z, 0, 0, 0);
            sc11 = __builtin_amdgcn_mfma_f32_16x16x32_bf16(qa1, kb1, z, 0, 0, 0);
        }
        __syncthreads();                  // all Q/K reads done before P overlay
        short* Ph = Ps + h * 32 * PVS;
        int j0 = cc, j1 = 16 + cc;
#pragma unroll
        for (int it = 0; it < 2; it++) {
            if (it == 1 && fast) break;
            f32x4 sj0 = it ? sc10 : sc00;
            f32x4 sj1 = it ? sc11 : sc01;
#pragma unroll
            for (int r = 0; r < 4; r++) {
                int i = it * 16 + quad * 4 + r;
                int at = start + i; if (at > N_ - 1) at = N_ - 1;  // clamp (rows>=L unused)
                const int* wrow = win + (size_t)(b * N_ + at) * MAXL;
                const float* brow = biasT + (size_t)(b * N_ + at) * MAXL * 4;
                float s0 = sj0[r] * scale;
                float s1 = fast ? -1e30f : sj1[r] * scale;
                int pw0 = (j0 < L) ? wrow[(start + j0) & 31] : 0;
                if (pw0 > 0) s0 += brow[((start + j0) & 31) * 4 + h];
                if (!fast) {
                    int pw1 = (j1 < L) ? wrow[(start + j1) & 31] : 0;
                    if (pw1 > 0) s1 += brow[((start + j1) & 31) * 4 + h];
                    if (j1 >= L) s1 = -1e30f;
                }
                if (j0 >= L) s0 = -1e30f;
                float m = fmaxf(s0, s1);
                m = fmaxf(m, __shfl_xor(m, 1));
                m = fmaxf(m, __shfl_xor(m, 2));
                m = fmaxf(m, __shfl_xor(m, 4));
                m = fmaxf(m, __shfl_xor(m, 8));
                float e0 = __expf(s0 - m), e1 = __expf(s1 - m);
                float sm = e0 + e1;
                sm += __shfl_xor(sm, 1);
                sm += __shfl_xor(sm, 2);
                sm += __shfl_xor(sm, 4);
                sm += __shfl_xor(sm, 8);
                float inv = 1.f / sm;
                Ph[i * PVS + j0] = bf16r(e0 * inv);
                Ph[i * PVS + j1] = bf16r(e1 * inv);   // exact 0 when masked
            }
        }
        __syncthreads();
        // PV: out^T[d][i] = sum_j V^T[d][j] P^T[j][i]
        const short* Vh = VT + h * 32 * PVS;
        bf16x8 va0 = *(const bf16x8*)(Vh + rb * PVS + quad * 8);
        bf16x8 va1 = *(const bf16x8*)(Vh + (16 + rb) * PVS + quad * 8);
        bf16x8 pb0 = *(const bf16x8*)(Ph + rb * PVS + quad * 8);
        f32x4 ot00 = __builtin_amdgcn_mfma_f32_16x16x32_bf16(va0, pb0, z, 0, 0, 0);
        f32x4 ot10 = __builtin_amdgcn_mfma_f32_16x16x32_bf16(va1, pb0, z, 0, 0, 0);
#pragma unroll
        for (int r = 0; r < 4; r++) {
            As[cc * LDSP + h * 32 + quad * 4 + r]      = bf16r(ot00[r]);
            As[cc * LDSP + h * 32 + 16 + quad * 4 + r] = bf16r(ot10[r]);
        }
        if (!fast) {
            bf16x8 pb1 = *(const bf16x8*)(Ph + (16 + rb) * PVS + quad * 8);
            f32x4 ot01 = __builtin_amdgcn_mfma_f32_16x16x32_bf16(va0, pb1, z, 0, 0, 0);
            f32x4 ot11 = __builtin_amdgcn_mfma_f32_16x16x32_bf16(va1, pb1, z, 0, 0, 0);
#pragma unroll
            for (int r = 0; r < 4; r++) {
                As[(16 + cc) * LDSP + h * 32 + quad * 4 + r]      = bf16r(ot01[r]);
                As[(16 + cc) * LDSP + h * 32 + 16 + quad * 4 + r] = bf16r(ot11[r]);
            }
        }
    }
    __syncthreads();

    // ---- S3: outproj + gate + residual -> val (f32 LDS) ---------------------
    if (!fast || wave < 2) {
        f32x4 a3[4];
#pragma unroll
        for (int i = 0; i < 4; i++)
#pragma unroll
            for (int r = 0; r < 4; r++) a3[i][r] = 0.f;
        gemm_a<4, 4, 4, LDSP>(As + (wave >> 1) * 16 * LDSP, pwo, (wave & 1) * 4, lane, a3);
#pragma unroll
        for (int ntl = 0; ntl < 4; ntl++) {
            int gcol = ((wave & 1) * 4 + ntl) * 16 + cc;
#pragma unroll
            for (int r = 0; r < 4; r++) {
                int lrow = (wave >> 1) * 16 + quad * 4 + r;
                int garow = start + lrow; if (garow > N_ - 1) garow = N_ - 1;
                float v = c_atom[(size_t)(b * N_ + garow) * DA + gcol]
                        + sgf[lrow * 128 + gcol] * a3[ntl][r];
                valf[lrow * 128 + gcol] = v;
            }
        }
    }
    __syncthreads();

    // ---- S3b: LN2 rows -> h (bf16, stride LDSP, in A region) ----------------
    {
        int row = tid >> 3, sub = tid & 7;       // 8 thr/row, 16 cols each
        if (!fast || row < 16) {
            const float* vr = valf + row * 128 + sub * 16;
            float4 x[4];
            float s = 0.f, sq = 0.f;
#pragma unroll
            for (int i = 0; i < 4; i++) {
                x[i] = *(const float4*)(vr + i * 4);
                s  += x[i].x + x[i].y + x[i].z + x[i].w;
                sq += x[i].x * x[i].x + x[i].y * x[i].y + x[i].z * x[i].z + x[i].w * x[i].w;
            }
            s += __shfl_xor(s, 1); sq += __shfl_xor(sq, 1);
            s += __shfl_xor(s, 2); sq += __shfl_xor(sq, 2);
            s += __shfl_xor(s, 4); sq += __shfl_xor(sq, 4);
            float mean = s * (1.f / 128.f);
            float var = sq * (1.f / 128.f) - mean * mean;
            float inv = rsqrtf(var + 1e-5f);
            short* hr = As + row * LDSP + sub * 16;
            const float* gp = lnfg + sub * 16;
            const float* bp = lnfb + sub * 16;
#pragma unroll
            for (int i = 0; i < 4; i++) {
                hr[i * 4 + 0] = bf16r((x[i].x - mean) * inv * gp[i * 4 + 0] + bp[i * 4 + 0]);
                hr[i * 4 + 1] = bf16r((x[i].y - mean) * inv * gp[i * 4 + 1] + bp[i * 4 + 1]);
                hr[i * 4 + 2] = bf16r((x[i].z - mean) * inv * gp[i * 4 + 2] + bp[i * 4 + 2]);
                hr[i * 4 + 3] = bf16r((x[i].w - mean) * inv * gp[i * 4 + 3] + bp[i * 4 + 3]);
            }
        }
    }
    __syncthreads();

    // ---- S4/S5: ffn1 (chunked over DFF/2) + ffn2 accumulation ---------------
    f32x4 c3a[4];
#pragma unroll
    for (int i = 0; i < 4; i++)
#pragma unroll
        for (int r = 0; r < 4; r++) c3a[i][r] = 0.f;
#pragma unroll
    for (int ch = 0; ch < 2; ch++) {
        f32x4 u0[8], u1[8];
#pragma unroll
        for (int i = 0; i < 8; i++)
#pragma unroll
            for (int r = 0; r < 4; r++) { u0[i][r] = 0.f; u1[i][r] = 0.f; }
        const short* bp12 = pw12 + ch * 32 * 4 * 512;
        gemm_a<4, 4, 8, LDSP>(As, bp12, wave * 8, lane, u0);
        if (!fast) gemm_a<4, 4, 8, LDSP>(As + 16 * LDSP, bp12, wave * 8, lane, u1);
#pragma unroll
        for (int rt = 0; rt < 2; rt++) {
            if (rt == 1 && fast) break;
            f32x4* ac = rt ? u1 : u0;
#pragma unroll
            for (int nt = 0; nt < 8; nt++) {
                int col8 = (wave * 8 + nt) * 8 + (cc >> 1);   // real chunk-local col
#pragma unroll
                for (int r = 0; r < 4; r++) {
                    float v = ac[nt][r];
                    float p = __shfl_xor(v, 1);               // partner (w2)
                    if (!(lane & 1)) {
                        float sil = v / (1.f + __expf(-v));
                        us[(rt * 16 + quad * 4 + r) * 264 + col8] = bf16r(sil * p);
                    }
                }
            }
        }
        __syncthreads();
        if (!fast || wave < 2)
            gemm_a<8, 16, 4, 264>(us + (wave >> 1) * 16 * 264, pw3 + ch * 8 * 512,
                                  (wave & 1) * 4, lane, c3a);
        __syncthreads();
    }

    // ---- S6: q2 = bf16(val + ffn2) ------------------------------------------
    if (!fast || wave < 2) {
#pragma unroll
        for (int ntl = 0; ntl < 4; ntl++) {
            int gcol = ((wave & 1) * 4 + ntl) * 16 + cc;
#pragma unroll
            for (int r = 0; r < 4; r++) {
                int lrow = (wave >> 1) * 16 + quad * 4 + r;
                q2s[lrow * 128 + gcol] = bf16r(valf[lrow * 128 + gcol] + c3a[ntl][r]);
            }
        }
    }
    __syncthreads();

    // ---- S7: segment mean -> row 0 of mean tile -----------------------------
    if (tid < 128) {
        int col = tid;
        float sum = 0.f;
        for (int i = 0; i < L; i++) sum += bf2f(q2s[i * 128 + col]);
        float inv = (L > 0) ? 1.f / (float)L : 0.f;
        mrs[col] = bf16r(sum * inv);
    }
    __syncthreads();

    // ---- S8: out[token] = mean @ tok_w + tok_b ------------------------------
    {
        f32x4 a8[8];
#pragma unroll
        for (int i = 0; i < 8; i++)
#pragma unroll
            for (int r = 0; r < 4; r++) a8[i][r] = 0.f;
        gemm_a<4, 4, 8, LDSP>(mrs, ptok, wave * 8, lane, a8);
        if (quad == 0) {                      // C row 0 = quad 0, r 0
#pragma unroll
            for (int nt = 0; nt < 8; nt++) {
                int col = (wave * 8 + nt) * 16 + cc;
                out[(size_t)token * DM + col] = a8[nt][0] + tb[col];
            }
        }
    }
}

extern "C" void kernel_launch(void* const* d_in, const int* in_sizes, int n_in,
                              void* d_out, int out_size, void* d_ws, size_t ws_size,
                              hipStream_t stream) {
    const float* c_atom  = (const float*)d_in[0];
    const float* p_lm    = (const float*)d_in[1];
    const int*   p_idx   = (const int*)d_in[2];
    const int*   tok     = (const int*)d_in[3];
    // d_in[4] = n_tokens (512, hardcoded)
    const float* ln_a_g  = (const float*)d_in[5];
    const float* ln_a_b  = (const float*)d_in[6];
    const float* w_q     = (const float*)d_in[7];
    const float* w_k     = (const float*)d_in[8];
    const float* w_v     = (const float*)d_in[9];
    const float* w_g     = (const float*)d_in[10];
    const float* w_o     = (const float*)d_in[11];
    const float* pb_w    = (const float*)d_in[12];
    const float* pb_b    = (const float*)d_in[13];
    const float* ln_f_g  = (const float*)d_in[14];
    const float* ln_f_b  = (const float*)d_in[15];
    const float* sw_w1   = (const float*)d_in[16];
    const float* sw_w2   = (const float*)d_in[17];
    const float* sw_w3   = (const float*)d_in[18];
    const float* tok_w   = (const float*)d_in[19];
    const float* tok_b   = (const float*)d_in[20];
    float* out = (float*)d_out;

    // ---------------- workspace layout ---------------------------------------
    float* ws = (float*)d_ws;
    int*   cnt   = (int*)ws;                       // 1024 i
    int*   tst   = cnt + 1024;                     // 1024 i
    int*   win   = tst + 1024;                     // 131072 i (poison = no winner)
    short* pqkvg = (short*)(win + 131072);         // 65536 bf16
    short* pwo   = pqkvg + 65536;                  // 16384 bf16
    short* pw12  = pwo + 16384;                    // 131072 bf16
    short* pw3   = pw12 + 131072;                  // 65536 bf16
    short* ptok  = pw3 + 65536;                    // 65536 bf16
    short* hln   = ptok + 65536;                   // 524288 bf16 (LN1 rows)
    float* biasT = (float*)(hln + 524288);         // 131072*4 f (winner bias)

    setup_kernel<<<91, 1024, 0, stream>>>(w_q, w_k, w_v, w_g, w_o, sw_w1, sw_w2,
                                          sw_w3, tok_w, tok, p_idx,
                                          c_atom, ln_a_g, ln_a_b,
                                          pqkvg, pwo, pw12, pw3, ptok, hln,
                                          cnt, tst, win);

    biasfill<<<32, 1024, 0, stream>>>(p_idx, tok, win, p_lm, pb_w, pb_b, biasT);

    tokfused<<<dim3(B_ * NT), dim3(256), 0, stream>>>(
        hln, c_atom, biasT, tst, cnt, win,
        pqkvg, pwo, pw12, pw3, ptok,
        ln_f_g, ln_f_b, tok_b, out);
}